// Round 6
// baseline (142.209 us; speedup 1.0000x reference)
//
#include <hip/hip_runtime.h>
#include <hip/hip_bf16.h>
#include <math.h>

#define NN 1024
#define LDIM 32
#define HDIM 64

// ---------------- fp32 workspace layout (float offsets) ----------------
#define WS_SELF 0                        // N*L   self_term [i][l]
#define WS_AA   (WS_SELF + NN*LDIM)      // N*H   Ea = 2^(2log2e * a_i) [i][h]
#define WS_CI   (WS_AA   + NN*HDIM)      // N*L   Ei = 2^(-log2e*(ci+bc)) [i][l]
#define WS_AGG  (WS_CI   + NN*LDIM)      // N     sigmoid(aggr)
#define WS_BI2  (WS_AGG  + NN)           // H     bi2 (UNSCALED - Pade epilogue)
#define WS_BI3  (WS_BI2  + HDIM)         // L     bi3 (unscaled)
#define WS_FEND (WS_BI3  + LDIM)

// ---------------- bf16(u16) region (short offsets from wsu) -------------
#define U_BJB  0                         // N*H   Eb = 2^(2log2e * b_j) [j][h]
#define U_HJB  (U_BJB + NN*HDIM)         // N*L   h   [j][l]
#define U_JT   (U_HJB + NN*LDIM)         // N*16*8 paired {h0,h1}{Ej0,Ej1}{pc0,pc1}{ps0,ps1}
#define U_W2B  (U_JT  + NN*LDIM*4)       // H*H   Wi2 [n][k] (UNSCALED)
#define U_W3B  (U_W2B + HDIM*HDIM)       // L*H   Wi3 [l][k] (unscaled)
#define U_END  (U_W3B + LDIM*HDIM)

// packed-pair transposed weight tables in precompute LDS (uint offsets)
#define PK_W1  0        // 16*64   Ws1
#define PK_W2  1024     // 32*64   Ws2
#define PK_W3  3072     // 32*32   Ws3
#define PK_WI1 4096     // 64*64   Wi1
#define PK_WC  8192     // 32*32   Wc
#define PK_END 9216     // 36 KB

#define K2P  2.88539008f     // 2*log2(e)
#define K1N  (-1.44269504f)  // -log2(e)

typedef __attribute__((ext_vector_type(8))) short bf16x8;
typedef __attribute__((ext_vector_type(4))) float f32x4;
typedef __attribute__((ext_vector_type(2))) float v2f;

__device__ __forceinline__ float fast_rcp(float x) { return __builtin_amdgcn_rcpf(x); }
__device__ __forceinline__ float fast_tanh(float x) {          // full version (precompute)
    float e = __builtin_amdgcn_exp2f(x * K2P);
    return 1.0f - 2.0f * fast_rcp(e + 1.0f);
}
__device__ __forceinline__ float fast_sigmoid(float x) {       // full version (precompute)
    return fast_rcp(1.0f + __builtin_amdgcn_exp2f(x * K1N));
}
__device__ __forceinline__ float blo(unsigned int u) { union { unsigned int i; float f; } v; v.i = u << 16; return v.f; }
__device__ __forceinline__ float bhi(unsigned int u) { union { unsigned int i; float f; } v; v.i = u & 0xffff0000u; return v.f; }
__device__ __forceinline__ float bf2f(unsigned short u) { union { unsigned int i; float f; } v; v.i = ((unsigned int)u) << 16; return v.f; }
__device__ __forceinline__ unsigned short f2bf(float f) {
    __hip_bfloat16 b = __float2bfloat16(f);
    unsigned short u; __builtin_memcpy(&u, &b, 2); return u;
}
__device__ __forceinline__ unsigned int pk2(float a, float b) {
    float2 t; t.x = a; t.y = b;
    __hip_bfloat162 h = __float22bfloat162_rn(t);
    unsigned int u; __builtin_memcpy(&u, &h, 4); return u;
}

// factored paired tanh, UN-paired rcp: trans pipe has slack (R4/R5 null),
// VALU issue slots are the wall. 2 VALU + 2 trans vs 5 VALU + 1 trans.
__device__ __forceinline__ v2f tanh2_fact(v2f ea, v2f eb) {
    v2f d = ea * eb + 1.0f;
    v2f r; r.x = fast_rcp(d.x); r.y = fast_rcp(d.y);
    return 1.0f - 2.0f * r;
}

// ------------- kernel 1: precompute (weights packed in-block) -------------
__global__ __launch_bounds__(256) void precompute(
    const float* __restrict__ state,
    const float* __restrict__ Ws1, const float* __restrict__ bs1,
    const float* __restrict__ Ws2, const float* __restrict__ bs2,
    const float* __restrict__ Ws3, const float* __restrict__ bs3,
    const float* __restrict__ Wi1, const float* __restrict__ bi1,
    const float* __restrict__ Wi2, const float* __restrict__ bi2,
    const float* __restrict__ Wi3, const float* __restrict__ bi3,
    const float* __restrict__ phw, const float* __restrict__ Wc,
    const float* __restrict__ bc,  const float* __restrict__ aggr,
    float* __restrict__ ws, unsigned short* __restrict__ wsu) {
    const int tid = threadIdx.x;
    const int w = tid >> 6, t = tid & 63;
    const int i = blockIdx.x * 4 + w;

    __shared__ unsigned int wlds[PK_END];
    __shared__ float shh[4][32], shdh[4][32], sht1[4][64], sht2[4][64];
    __shared__ float shph[4];

    {
        const float2* s1 = (const float2*)Ws1;
        #pragma unroll
        for (int r = 0; r < 4; r++) { int e = tid + r * 256; int f = e >> 4, k2 = e & 15;
            float2 v = s1[e]; wlds[PK_W1 + k2 * 64 + f] = pk2(v.x, v.y); }
        const float2* s2 = (const float2*)Ws2;
        #pragma unroll
        for (int r = 0; r < 8; r++) { int e = tid + r * 256; int f = e >> 5, k2 = e & 31;
            float2 v = s2[e]; wlds[PK_W2 + k2 * 64 + f] = pk2(v.x, v.y); }
        const float2* s3 = (const float2*)Ws3;
        #pragma unroll
        for (int r = 0; r < 4; r++) { int e = tid + r * 256; int f = e >> 5, k2 = e & 31;
            float2 v = s3[e]; wlds[PK_W3 + k2 * 32 + f] = pk2(v.x, v.y); }
        const float2* si = (const float2*)Wi1;
        #pragma unroll
        for (int r = 0; r < 16; r++) { int e = tid + r * 256; int f = e >> 6, c2 = e & 63;
            float2 v = si[e]; wlds[PK_WI1 + c2 * 64 + f] = pk2(v.x, v.y); }
        const float2* sc = (const float2*)Wc;
        #pragma unroll
        for (int r = 0; r < 4; r++) { int e = tid + r * 256; int f = e >> 5, c2 = e & 31;
            float2 v = sc[e]; wlds[PK_WC + c2 * 32 + f] = pk2(v.x, v.y); }
    }
    if (blockIdx.x == 0) {
        // Wi2/bi2 UNSCALED: pair epilogue uses Pade tanh, not exp2
        #pragma unroll
        for (int r = 0; r < 16; r++) { int e = tid + r * 256; wsu[U_W2B + e] = f2bf(Wi2[e]); }
        #pragma unroll
        for (int r = 0; r < 8; r++)  { int e = tid + r * 256; wsu[U_W3B + e] = f2bf(Wi3[e]); }
        if (tid < HDIM) ws[WS_BI2 + tid] = bi2[tid];
        if (tid < LDIM) ws[WS_BI3 + tid] = bi3[tid];
    }

    float sv = (t < 33) ? state[i * 33 + t] : 0.f;
    if (t < 32) shh[w][t] = sv;
    if (t == 32) shph[w] = sv;
    if (t == 33) ws[WS_AGG + i] = fast_sigmoid(aggr[i]);
    __syncthreads();

    {
        float s = bs1[t];
        const unsigned int* W = wlds + PK_W1;
        #pragma unroll
        for (int k2 = 0; k2 < 16; k2++) {
            unsigned int p = W[k2 * 64 + t];
            s = fmaf(blo(p), shh[w][2 * k2], s);
            s = fmaf(bhi(p), shh[w][2 * k2 + 1], s);
        }
        sht1[w][t] = fast_tanh(s);
    }
    __syncthreads();
    {
        float s = bs2[t];
        const unsigned int* W = wlds + PK_W2;
        #pragma unroll
        for (int k2 = 0; k2 < 32; k2++) {
            unsigned int p = W[k2 * 64 + t];
            s = fmaf(blo(p), sht1[w][2 * k2], s);
            s = fmaf(bhi(p), sht1[w][2 * k2 + 1], s);
        }
        sht2[w][t] = fast_tanh(s);
    }
    __syncthreads();
    if (t < 32) {
        float s = bs3[t];
        const unsigned int* W = wlds + PK_W3;
        #pragma unroll
        for (int k2 = 0; k2 < 32; k2++) {
            unsigned int p = W[k2 * 32 + t];
            s = fmaf(blo(p), sht2[w][2 * k2], s);
            s = fmaf(bhi(p), sht2[w][2 * k2 + 1], s);
        }
        ws[WS_SELF + i * 32 + t] = s;
        shdh[w][t] = s;
    }
    __syncthreads();
    {
        float sa = 0.f, sb = bi1[t];
        const unsigned int* W = wlds + PK_WI1;
        #pragma unroll
        for (int k2 = 0; k2 < 16; k2++) {
            float h0 = shh[w][2 * k2], h1 = shh[w][2 * k2 + 1];
            float d0 = shdh[w][2 * k2], d1 = shdh[w][2 * k2 + 1];
            unsigned int wa  = W[k2 * 64 + t];
            unsigned int wb  = W[(16 + k2) * 64 + t];
            unsigned int wa2 = W[(32 + k2) * 64 + t];
            unsigned int wb2 = W[(48 + k2) * 64 + t];
            sa = fmaf(blo(wa), h0, sa);  sa = fmaf(bhi(wa), h1, sa);
            sb = fmaf(blo(wb), h0, sb);  sb = fmaf(bhi(wb), h1, sb);
            sa = fmaf(blo(wa2), d0, sa); sa = fmaf(bhi(wa2), d1, sa);
            sb = fmaf(blo(wb2), d0, sb); sb = fmaf(bhi(wb2), d1, sb);
        }
        // exp-factorized: store E = 2^(pre-scaled logit) instead of logit
        ws[WS_AA + i * 64 + t]  = __builtin_amdgcn_exp2f(sa * K2P);
        wsu[U_BJB + i * 64 + t] = f2bf(__builtin_amdgcn_exp2f(sb * K2P));
    }
    if (t < 32) {
        float si2 = 0.f, sj = 0.f;
        const unsigned int* W = wlds + PK_WC;
        #pragma unroll
        for (int m2 = 0; m2 < 16; m2++) {
            float h0 = shh[w][2 * m2], h1 = shh[w][2 * m2 + 1];
            unsigned int wi = W[m2 * 32 + t];
            unsigned int wj = W[(16 + m2) * 32 + t];
            si2 = fmaf(blo(wi), h0, si2); si2 = fmaf(bhi(wi), h1, si2);
            sj  = fmaf(blo(wj), h0, sj);  sj  = fmaf(bhi(wj), h1, sj);
        }
        // Ei = 2^(-log2e*(ci+bc)); sigmoid(ci+cj) = rcp(1 + Ei*Ej)
        ws[WS_CI + i * 32 + t] = __builtin_amdgcn_exp2f((si2 + bc[t]) * K1N);
        float h = shh[w][t];
        wsu[U_HJB + i * 32 + t] = f2bf(h);
        float ejn = __builtin_amdgcn_exp2f(sj * K1N);
        float sc_, cc_;
        __sincosf(shph[w] * phw[t], &sc_, &cc_);
        // pair (l, l+16) into one bf16 uint4 for stage-C pk math
        int p = (t & 15) + 16;                       // partner lane (self for t>=16)
        float h_p  = __shfl(h,   p);
        float e_p  = __shfl(ejn, p);
        float cc_p = __shfl(cc_, p);
        float sc_p = __shfl(sc_, p);
        if (t < 16) {
            uint4 o; o.x = pk2(h, h_p); o.y = pk2(ejn, e_p);
            o.z = pk2(cc_, cc_p); o.w = pk2(sc_, sc_p);
            *(uint4*)(wsu + U_JT + (i * 16 + t) * 8) = o;
        }
    }
}

// ------------- kernel 2: MFMA pairwise core (1 block per i) ---------------
// Diet v6 (VALU de-bloat): R4/R5 proved trans pipe has slack; VALU issue
// slots are the wall. (a) UN-pair all shared rcps -- paired-rcp spends ~4
// full-rate VALU ops to save 1 quarter-rate trans op, the wrong trade now
// (~-50 VALU ops/body, +28 trans). (b) single-buffer x2ls: stageB(T-1)
// runs at body top BEFORE the epilogue writes tile T -- per-wave program
// order makes the double buffer redundant; -9.2KB LDS. (c) const-ref
// uint4 params (no lambda copies). Occupancy still grid-capped at 16
// waves/CU (1024 blocks = 4/CU exactly); VGPR 100 would allow 20.
__global__ __launch_bounds__(256) void pair_kernel(
    const float* __restrict__ ws, const unsigned short* __restrict__ wsu,
    float* __restrict__ out) {
    const int i    = blockIdx.x;
    const int tid  = threadIdx.x;
    const int w    = tid >> 6;
    const int lane = tid & 63;
    const int q    = lane >> 4;
    const int m    = lane & 15;
    const int jw   = w * 16;
    const int sub  = lane & 3;

    __shared__ unsigned short W2ls[64 * 72];
    __shared__ unsigned short x2ls[4 * 16 * 72];       // per-wave SINGLE buffer
    __shared__ float redT[4][32], redU[4][32], redV[4][32];
    __shared__ float sfw[4];

    // ---- setup ----
    {
        int row = tid >> 2, c = (tid & 3) * 16;
        const uint4* s2 = (const uint4*)(wsu + U_W2B + row * 64 + c);
        uint4 d0 = s2[0], d1 = s2[1];
        uint4* dd = (uint4*)(&W2ls[row * 72 + c]);
        dd[0] = d0; dd[1] = d1;
    }
    // W3 fragments: constant per thread across all bodies -> registers
    bf16x8 w3r[2][2];
    #pragma unroll
    for (int lb = 0; lb < 2; lb++)
        #pragma unroll
        for (int s = 0; s < 2; s++)
            w3r[lb][s] = *(const bf16x8*)(wsu + U_W3B + (lb * 16 + m) * 64 + s * 32 + q * 8);

    v2f hi2[4];                     // own h pairs for fac
    {
        uint4 hv4 = *(const uint4*)(wsu + U_HJB + i * 32 + sub * 8);
        unsigned int hd[4] = {hv4.x, hv4.y, hv4.z, hv4.w};
        #pragma unroll
        for (int e = 0; e < 4; e++) { hi2[e].x = blo(hd[e]); hi2[e].y = bhi(hd[e]); }
    }
    f32x4 b2q[4];              // bias slice for MFMA C-init (unscaled)
    #pragma unroll
    for (int nb = 0; nb < 4; nb++) {
        float4 bv = *(const float4*)(ws + WS_BI2 + nb * 16 + q * 4);
        b2q[nb][0] = bv.x; b2q[nb][1] = bv.y; b2q[nb][2] = bv.z; b2q[nb][3] = bv.w;
    }
    // Ea = 2^(pre-scaled a_i): loop-invariant across all tiles, in registers
    v2f ea2[8];
    {
        const float* ap = ws + WS_AA + i * 64 + q * 8;
        #pragma unroll
        for (int s = 0; s < 2; s++) {
            float4 lo = *(const float4*)(ap + s * 32);
            float4 hi = *(const float4*)(ap + s * 32 + 4);
            ea2[s * 4 + 0].x = lo.x; ea2[s * 4 + 0].y = lo.y;
            ea2[s * 4 + 1].x = lo.z; ea2[s * 4 + 1].y = lo.w;
            ea2[s * 4 + 2].x = hi.x; ea2[s * 4 + 2].y = hi.y;
            ea2[s * 4 + 3].x = hi.z; ea2[s * 4 + 3].y = hi.w;
        }
    }
    v2f hiv2, ei2;             // (l=m, l=m+16) pairs for stage C
    hiv2.x = bf2f(wsu[U_HJB + i * 32 + m]);      hiv2.y = bf2f(wsu[U_HJB + i * 32 + 16 + m]);
    ei2.x = ws[WS_CI + i * 32 + m];              ei2.y = ws[WS_CI + i * 32 + 16 + m];
    const float aggi = ws[WS_AGG + i];
    const float sub0 = (sub == 0) ? 1.0f : 0.0f;

    // ---- streaming pointers + tile-0 prefetch ----
    const unsigned short* hp = wsu + U_HJB + (jw + (lane >> 2)) * 32 + sub * 8;
    const unsigned short* bp = wsu + U_BJB + (jw + m) * 64 + q * 8;
    const unsigned short* jp = wsu + U_JT + ((jw + q * 4) * 16 + m) * 8;

    uint4 hvA = *(const uint4*)hp;
    uint4 b0A = *(const uint4*)bp;
    uint4 b1A = *(const uint4*)(bp + 32);
    uint4 hvB, b0B, b1B;
    __syncthreads();

    // persistent accumulators
    f32x4 accK[2];
    #pragma unroll
    for (int lb = 0; lb < 2; lb++) { accK[lb][0]=0.f; accK[lb][1]=0.f; accK[lb][2]=0.f; accK[lb][3]=0.f; }
    v2f u2; u2.x = 0.f; u2.y = 0.f;
    v2f vv2; vv2.x = 0.f; vv2.y = 0.f;
    float sumfac = 0.f;

    unsigned short* xb = &x2ls[w * 1152];

    auto stageB = [&]() {
        bf16x8 x2f[2];
        #pragma unroll
        for (int s = 0; s < 2; s++)
            x2f[s] = *(const bf16x8*)(&xb[m * 72 + s * 32 + q * 8]);
        #pragma unroll
        for (int lb = 0; lb < 2; lb++) {
            #pragma unroll
            for (int s = 0; s < 2; s++) {
                accK[lb] = __builtin_amdgcn_mfma_f32_16x16x32_bf16(x2f[s], w3r[lb][s], accK[lb], 0, 0, 0);
            }
        }
    };

    auto body = [&](int T, const uint4& hvc, const uint4& b0c, const uint4& b1c,
                    uint4& hvn, uint4& b0n, uint4& b1n) {
        // prefetch next tile's h/b
        hp += 2048; bp += 4096;
        hvn = *(const uint4*)hp;
        b0n = *(const uint4*)bp;
        b1n = *(const uint4*)(bp + 32);

        // jt loads for CURRENT tile issued at body TOP -- consumed at body
        // end (stage C)
        uint4 jt4[4];
        #pragma unroll
        for (int r = 0; r < 4; r++) jt4[r] = *(const uint4*)(jp + r * 128);
        jp += 8192;

        // deferred stage B for previous tile; reads xb BEFORE this body's
        // epilogue overwrites it (per-wave program order = correctness)
        if (T > 0) stageB();

        // 1) fac (lane owns j = T*64 + jw + (lane>>2)); zeroed at j==i
        float facm;
        {
            unsigned int hd[4] = {hvc.x, hvc.y, hvc.z, hvc.w};
            v2f s2v; s2v.x = 0.f; s2v.y = 0.f;
            #pragma unroll
            for (int e = 0; e < 4; e++) {
                v2f hj; hj.x = blo(hd[e]); hj.y = bhi(hd[e]);
                v2f d = hi2[e] - hj;
                s2v += d * d;                      // v_pk_fma
            }
            float s = s2v.x + s2v.y;
            s += __shfl_xor(s, 1); s += __shfl_xor(s, 2);
            int jj = T * 64 + jw + (lane >> 2);
            float facown = fminf(__builtin_amdgcn_rsqf(s), 2.0f) * aggi;
            facown = (jj == i) ? 0.0f : facown;
            sumfac = fmaf(sub0, facown, sumfac);
            facm = __shfl(facown, 4 * m);
        }

        // 2) x1 B-fragments: factored tanh (pk fma + 2 rcp, no exp2)
        bf16x8 afr[2];
        {
            unsigned int bd[8] = {b0c.x, b0c.y, b0c.z, b0c.w, b1c.x, b1c.y, b1c.z, b1c.w};
            #pragma unroll
            for (int s = 0; s < 2; s++) {
                union { uint4 u4; bf16x8 v; } pkd;
                #pragma unroll
                for (int e = 0; e < 4; e++) {
                    unsigned int bw = bd[s * 4 + e];
                    v2f eb; eb.x = blo(bw); eb.y = bhi(bw);
                    v2f t2 = tanh2_fact(ea2[s * 4 + e], eb);
                    ((unsigned int*)&pkd.u4)[e] = pk2(t2.x, t2.y);
                }
                afr[s] = pkd.v;
            }
        }

        // 3) stage A: X2^T = Wi2' * X1^T, C-init = bias (unscaled logit out)
        f32x4 accA[4];
        #pragma unroll
        for (int nb = 0; nb < 4; nb++) {
            f32x4 acc = b2q[nb];
            #pragma unroll
            for (int s = 0; s < 2; s++) {
                bf16x8 w2f = *(const bf16x8*)(&W2ls[(nb * 16 + m) * 72 + s * 32 + q * 8]);
                acc = __builtin_amdgcn_mfma_f32_16x16x32_bf16(w2f, afr[s], acc, 0, 0, 0);
            }
            accA[nb] = acc;
        }
        // epilogue A: x2s = facm * tanh(z), Pade(15,6), per-element rcp
        #pragma unroll
        for (int nb = 0; nb < 4; nb++) {
            v2f zA; zA.x = accA[nb][0]; zA.y = accA[nb][1];
            v2f zB; zB.x = accA[nb][2]; zB.y = accA[nb][3];
            v2f zzA = zA * zA, zzB = zB * zB;
            v2f nA = zA * (zzA + 15.0f), nB = zB * (zzB + 15.0f);
            v2f dA = zzA * 6.0f + 15.0f, dB = zzB * 6.0f + 15.0f;
            v2f rA, rB;
            rA.x = fast_rcp(dA.x); rA.y = fast_rcp(dA.y);
            rB.x = fast_rcp(dB.x); rB.y = fast_rcp(dB.y);
            v2f tA = nA * (rA * facm);
            v2f tB = nB * (rB * facm);
            uint2 pk; pk.x = pk2(tA.x, tA.y); pk.y = pk2(tB.x, tB.y);
            *(uint2*)(&xb[m * 72 + nb * 16 + q * 4]) = pk;
        }

        // 5) stage C: quantum partials; coh = rcp(1 + Ei*Ej), per-elem rcp
        #pragma unroll
        for (int r = 0; r < 4; r++) {
            uint4 jv = jt4[r];
            v2f hj2; hj2.x = blo(jv.x); hj2.y = bhi(jv.x);
            v2f ej2; ej2.x = blo(jv.y); ej2.y = bhi(jv.y);
            v2f pc2; pc2.x = blo(jv.z); pc2.y = bhi(jv.z);
            v2f ps2; ps2.x = blo(jv.w); ps2.y = bhi(jv.w);
            v2f dd = ei2 * ej2 + 1.0f;
            v2f coh; coh.x = fast_rcp(dd.x); coh.y = fast_rcp(dd.y);
            v2f cd = coh * (hiv2 - hj2);
            u2  += cd * pc2;
            vv2 += cd * ps2;
        }
    };

    #pragma unroll 1
    for (int T = 0; T < 16; T += 2) {
        body(T,     hvA, b0A, b1A, hvB, b0B, b1B);
        body(T + 1, hvB, b0B, b1B, hvA, b0A, b1A);
    }
    stageB();   // tile 15

    // ---- final reductions ----
    float T1[2];
    float aU[2] = {u2.x, u2.y};
    float aV[2] = {vv2.x, vv2.y};
    #pragma unroll
    for (int lb = 0; lb < 2; lb++) {
        T1[lb] = (accK[lb][0] + accK[lb][1]) + (accK[lb][2] + accK[lb][3]);
        T1[lb] += __shfl_xor(T1[lb], 16); T1[lb] += __shfl_xor(T1[lb], 32);
        aU[lb] += __shfl_xor(aU[lb], 16); aU[lb] += __shfl_xor(aU[lb], 32);
        aV[lb] += __shfl_xor(aV[lb], 16); aV[lb] += __shfl_xor(aV[lb], 32);
    }
    sumfac += __shfl_xor(sumfac, 1);  sumfac += __shfl_xor(sumfac, 2);
    sumfac += __shfl_xor(sumfac, 4);  sumfac += __shfl_xor(sumfac, 8);
    sumfac += __shfl_xor(sumfac, 16); sumfac += __shfl_xor(sumfac, 32);
    if (lane < 16) {
        redT[w][m] = T1[0];      redT[w][16 + m] = T1[1];
        redU[w][m] = aU[0];      redU[w][16 + m] = aU[1];
        redV[w][m] = aV[0];      redV[w][16 + m] = aV[1];
    }
    if (lane == 0) sfw[w] = sumfac;
    __syncthreads();
    if (tid < 32) {
        int l = tid;
        float t1 = (redT[0][l] + redT[1][l]) + (redT[2][l] + redT[3][l]);
        float uu = (redU[0][l] + redU[1][l]) + (redU[2][l] + redU[3][l]);
        float vvv = (redV[0][l] + redV[1][l]) + (redV[2][l] + redV[3][l]);
        float sf = (sfw[0] + sfw[1]) + (sfw[2] + sfw[3]);
        int mm = l & 15;
        uint2 jti = *(const uint2*)(wsu + U_JT + (i * 16 + mm) * 8 + 4);  // cc/sc pair words
        float pic = (l < 16) ? blo(jti.x) : bhi(jti.x);
        float pis = (l < 16) ? blo(jti.y) : bhi(jti.y);
        float isum = t1 + sf * ws[WS_BI3 + l] - (pic * uu + pis * vvv);
        out[i * 33 + l] = 0.5f * ws[WS_SELF + i * 32 + l] + 0.3f * isum;
        // parallel |isum| tail reduce
        float ab = fabsf(isum);
        ab += __shfl_xor(ab, 1); ab += __shfl_xor(ab, 2);
        ab += __shfl_xor(ab, 4); ab += __shfl_xor(ab, 8);
        ab += __shfl_xor(ab, 16);
        if (tid == 0) out[i * 33 + 32] = 0.1f + 0.05f * ab;
    }
}

extern "C" void kernel_launch(void* const* d_in, const int* in_sizes, int n_in,
                              void* d_out, int out_size, void* d_ws, size_t ws_size,
                              hipStream_t stream) {
    const float* state   = (const float*)d_in[0];
    const float* Ws1     = (const float*)d_in[1];
    const float* bs1     = (const float*)d_in[2];
    const float* Ws2     = (const float*)d_in[3];
    const float* bs2     = (const float*)d_in[4];
    const float* Ws3     = (const float*)d_in[5];
    const float* bs3     = (const float*)d_in[6];
    const float* Wi1     = (const float*)d_in[7];
    const float* bi1     = (const float*)d_in[8];
    const float* Wi2     = (const float*)d_in[9];
    const float* bi2     = (const float*)d_in[10];
    const float* Wi3     = (const float*)d_in[11];
    const float* bi3     = (const float*)d_in[12];
    const float* phase_w = (const float*)d_in[13];
    const float* Wc      = (const float*)d_in[14];
    const float* bc      = (const float*)d_in[15];
    const float* aggr    = (const float*)d_in[16];

    float* ws = (float*)d_ws;
    unsigned short* wsu = (unsigned short*)(ws + WS_FEND);
    float* out = (float*)d_out;

    precompute<<<256, 256, 0, stream>>>(state, Ws1, bs1, Ws2, bs2, Ws3, bs3,
                                        Wi1, bi1, Wi2, bi2, Wi3, bi3,
                                        phase_w, Wc, bc, aggr, ws, wsu);
    pair_kernel<<<NN, 256, 0, stream>>>(ws, wsu, out);
}

// Round 7
// 138.551 us; speedup vs baseline: 1.0264x; 1.0264x over previous
//
#include <hip/hip_runtime.h>
#include <hip/hip_bf16.h>
#include <math.h>

#define NN 1024
#define LDIM 32
#define HDIM 64

// ---------------- fp32 workspace layout (float offsets) ----------------
#define WS_SELF 0                        // N*L   self_term [i][l]
#define WS_AA   (WS_SELF + NN*LDIM)      // N*H   Ea = 2^(2log2e * a_i) [i][h]
#define WS_CI   (WS_AA   + NN*HDIM)      // N*L   Ei = 2^(-log2e*(ci+bc)) [i][l]
#define WS_AGG  (WS_CI   + NN*LDIM)      // N     sigmoid(aggr)
#define WS_BI2  (WS_AGG  + NN)           // H     bi2 (UNSCALED - Pade epilogue)
#define WS_BI3  (WS_BI2  + HDIM)         // L     bi3 (unscaled)
#define WS_FEND (WS_BI3  + LDIM)

// ---------------- bf16(u16) region (short offsets from wsu) -------------
#define U_BJB  0                         // N*H   Eb = 2^(2log2e * b_j) [j][h]
#define U_HJB  (U_BJB + NN*HDIM)         // N*L   h   [j][l]
#define U_JT   (U_HJB + NN*LDIM)         // N*16*8 paired {h0,h1}{Ej0,Ej1}{pc0,pc1}{ps0,ps1}
#define U_W2B  (U_JT  + NN*LDIM*4)       // H*H   Wi2 [n][k] (UNSCALED)
#define U_W3B  (U_W2B + HDIM*HDIM)       // L*H   Wi3 [l][k] (unscaled)
#define U_END  (U_W3B + LDIM*HDIM)

// packed-pair transposed weight tables in precompute LDS (uint offsets)
#define PK_W1  0        // 16*64   Ws1
#define PK_W2  1024     // 32*64   Ws2
#define PK_W3  3072     // 32*32   Ws3
#define PK_WI1 4096     // 64*64   Wi1
#define PK_WC  8192     // 32*32   Wc
#define PK_END 9216     // 36 KB

#define K2P  2.88539008f     // 2*log2(e)
#define K1N  (-1.44269504f)  // -log2(e)

typedef __attribute__((ext_vector_type(8))) short bf16x8;
typedef __attribute__((ext_vector_type(4))) float f32x4;
typedef __attribute__((ext_vector_type(2))) float v2f;

__device__ __forceinline__ float fast_rcp(float x) { return __builtin_amdgcn_rcpf(x); }
__device__ __forceinline__ float fast_tanh(float x) {          // full version (precompute)
    float e = __builtin_amdgcn_exp2f(x * K2P);
    return 1.0f - 2.0f * fast_rcp(e + 1.0f);
}
__device__ __forceinline__ float fast_sigmoid(float x) {       // full version (precompute)
    return fast_rcp(1.0f + __builtin_amdgcn_exp2f(x * K1N));
}
__device__ __forceinline__ float blo(unsigned int u) { union { unsigned int i; float f; } v; v.i = u << 16; return v.f; }
__device__ __forceinline__ float bhi(unsigned int u) { union { unsigned int i; float f; } v; v.i = u & 0xffff0000u; return v.f; }
__device__ __forceinline__ float bf2f(unsigned short u) { union { unsigned int i; float f; } v; v.i = ((unsigned int)u) << 16; return v.f; }
__device__ __forceinline__ unsigned short f2bf(float f) {
    __hip_bfloat16 b = __float2bfloat16(f);
    unsigned short u; __builtin_memcpy(&u, &b, 2); return u;
}
__device__ __forceinline__ unsigned int pk2(float a, float b) {
    float2 t; t.x = a; t.y = b;
    __hip_bfloat162 h = __float22bfloat162_rn(t);
    unsigned int u; __builtin_memcpy(&u, &h, 4); return u;
}

// factored tanh (exp-factorized, no exp2 in loop)
__device__ __forceinline__ v2f tanh2_fact(v2f ea, v2f eb) {
    v2f d = ea * eb + 1.0f;
    v2f r; r.x = fast_rcp(d.x); r.y = fast_rcp(d.y);
    return 1.0f - 2.0f * r;
}

// ------------- kernel 1: precompute (weights packed in-block) -------------
__global__ __launch_bounds__(256) void precompute(
    const float* __restrict__ state,
    const float* __restrict__ Ws1, const float* __restrict__ bs1,
    const float* __restrict__ Ws2, const float* __restrict__ bs2,
    const float* __restrict__ Ws3, const float* __restrict__ bs3,
    const float* __restrict__ Wi1, const float* __restrict__ bi1,
    const float* __restrict__ Wi2, const float* __restrict__ bi2,
    const float* __restrict__ Wi3, const float* __restrict__ bi3,
    const float* __restrict__ phw, const float* __restrict__ Wc,
    const float* __restrict__ bc,  const float* __restrict__ aggr,
    float* __restrict__ ws, unsigned short* __restrict__ wsu) {
    const int tid = threadIdx.x;
    const int w = tid >> 6, t = tid & 63;
    const int i = blockIdx.x * 4 + w;

    __shared__ unsigned int wlds[PK_END];
    __shared__ float shh[4][32], shdh[4][32], sht1[4][64], sht2[4][64];
    __shared__ float shph[4];

    {
        const float2* s1 = (const float2*)Ws1;
        #pragma unroll
        for (int r = 0; r < 4; r++) { int e = tid + r * 256; int f = e >> 4, k2 = e & 15;
            float2 v = s1[e]; wlds[PK_W1 + k2 * 64 + f] = pk2(v.x, v.y); }
        const float2* s2 = (const float2*)Ws2;
        #pragma unroll
        for (int r = 0; r < 8; r++) { int e = tid + r * 256; int f = e >> 5, k2 = e & 31;
            float2 v = s2[e]; wlds[PK_W2 + k2 * 64 + f] = pk2(v.x, v.y); }
        const float2* s3 = (const float2*)Ws3;
        #pragma unroll
        for (int r = 0; r < 4; r++) { int e = tid + r * 256; int f = e >> 5, k2 = e & 31;
            float2 v = s3[e]; wlds[PK_W3 + k2 * 32 + f] = pk2(v.x, v.y); }
        const float2* si = (const float2*)Wi1;
        #pragma unroll
        for (int r = 0; r < 16; r++) { int e = tid + r * 256; int f = e >> 6, c2 = e & 63;
            float2 v = si[e]; wlds[PK_WI1 + c2 * 64 + f] = pk2(v.x, v.y); }
        const float2* sc = (const float2*)Wc;
        #pragma unroll
        for (int r = 0; r < 4; r++) { int e = tid + r * 256; int f = e >> 5, c2 = e & 31;
            float2 v = sc[e]; wlds[PK_WC + c2 * 32 + f] = pk2(v.x, v.y); }
    }
    if (blockIdx.x == 0) {
        // Wi2/bi2 UNSCALED: pair epilogue uses Pade tanh, not exp2
        #pragma unroll
        for (int r = 0; r < 16; r++) { int e = tid + r * 256; wsu[U_W2B + e] = f2bf(Wi2[e]); }
        #pragma unroll
        for (int r = 0; r < 8; r++)  { int e = tid + r * 256; wsu[U_W3B + e] = f2bf(Wi3[e]); }
        if (tid < HDIM) ws[WS_BI2 + tid] = bi2[tid];
        if (tid < LDIM) ws[WS_BI3 + tid] = bi3[tid];
    }

    float sv = (t < 33) ? state[i * 33 + t] : 0.f;
    if (t < 32) shh[w][t] = sv;
    if (t == 32) shph[w] = sv;
    if (t == 33) ws[WS_AGG + i] = fast_sigmoid(aggr[i]);
    __syncthreads();

    {
        float s = bs1[t];
        const unsigned int* W = wlds + PK_W1;
        #pragma unroll
        for (int k2 = 0; k2 < 16; k2++) {
            unsigned int p = W[k2 * 64 + t];
            s = fmaf(blo(p), shh[w][2 * k2], s);
            s = fmaf(bhi(p), shh[w][2 * k2 + 1], s);
        }
        sht1[w][t] = fast_tanh(s);
    }
    __syncthreads();
    {
        float s = bs2[t];
        const unsigned int* W = wlds + PK_W2;
        #pragma unroll
        for (int k2 = 0; k2 < 32; k2++) {
            unsigned int p = W[k2 * 64 + t];
            s = fmaf(blo(p), sht1[w][2 * k2], s);
            s = fmaf(bhi(p), sht1[w][2 * k2 + 1], s);
        }
        sht2[w][t] = fast_tanh(s);
    }
    __syncthreads();
    if (t < 32) {
        float s = bs3[t];
        const unsigned int* W = wlds + PK_W3;
        #pragma unroll
        for (int k2 = 0; k2 < 32; k2++) {
            unsigned int p = W[k2 * 32 + t];
            s = fmaf(blo(p), sht2[w][2 * k2], s);
            s = fmaf(bhi(p), sht2[w][2 * k2 + 1], s);
        }
        ws[WS_SELF + i * 32 + t] = s;
        shdh[w][t] = s;
    }
    __syncthreads();
    {
        float sa = 0.f, sb = bi1[t];
        const unsigned int* W = wlds + PK_WI1;
        #pragma unroll
        for (int k2 = 0; k2 < 16; k2++) {
            float h0 = shh[w][2 * k2], h1 = shh[w][2 * k2 + 1];
            float d0 = shdh[w][2 * k2], d1 = shdh[w][2 * k2 + 1];
            unsigned int wa  = W[k2 * 64 + t];
            unsigned int wb  = W[(16 + k2) * 64 + t];
            unsigned int wa2 = W[(32 + k2) * 64 + t];
            unsigned int wb2 = W[(48 + k2) * 64 + t];
            sa = fmaf(blo(wa), h0, sa);  sa = fmaf(bhi(wa), h1, sa);
            sb = fmaf(blo(wb), h0, sb);  sb = fmaf(bhi(wb), h1, sb);
            sa = fmaf(blo(wa2), d0, sa); sa = fmaf(bhi(wa2), d1, sa);
            sb = fmaf(blo(wb2), d0, sb); sb = fmaf(bhi(wb2), d1, sb);
        }
        // exp-factorized: store E = 2^(pre-scaled logit) instead of logit
        ws[WS_AA + i * 64 + t]  = __builtin_amdgcn_exp2f(sa * K2P);
        wsu[U_BJB + i * 64 + t] = f2bf(__builtin_amdgcn_exp2f(sb * K2P));
    }
    if (t < 32) {
        float si2 = 0.f, sj = 0.f;
        const unsigned int* W = wlds + PK_WC;
        #pragma unroll
        for (int m2 = 0; m2 < 16; m2++) {
            float h0 = shh[w][2 * m2], h1 = shh[w][2 * m2 + 1];
            unsigned int wi = W[m2 * 32 + t];
            unsigned int wj = W[(16 + m2) * 32 + t];
            si2 = fmaf(blo(wi), h0, si2); si2 = fmaf(bhi(wi), h1, si2);
            sj  = fmaf(blo(wj), h0, sj);  sj  = fmaf(bhi(wj), h1, sj);
        }
        // Ei = 2^(-log2e*(ci+bc)); sigmoid(ci+cj) = rcp(1 + Ei*Ej)
        ws[WS_CI + i * 32 + t] = __builtin_amdgcn_exp2f((si2 + bc[t]) * K1N);
        float h = shh[w][t];
        wsu[U_HJB + i * 32 + t] = f2bf(h);
        float ejn = __builtin_amdgcn_exp2f(sj * K1N);
        float sc_, cc_;
        __sincosf(shph[w] * phw[t], &sc_, &cc_);
        // pair (l, l+16) into one bf16 uint4 for stage-C pk math
        int p = (t & 15) + 16;                       // partner lane (self for t>=16)
        float h_p  = __shfl(h,   p);
        float e_p  = __shfl(ejn, p);
        float cc_p = __shfl(cc_, p);
        float sc_p = __shfl(sc_, p);
        if (t < 16) {
            uint4 o; o.x = pk2(h, h_p); o.y = pk2(ejn, e_p);
            o.z = pk2(cc_, cc_p); o.w = pk2(sc_, sc_p);
            *(uint4*)(wsu + U_JT + (i * 16 + t) * 8) = o;
        }
    }
}

// ------------- kernel 2: MFMA pairwise core (1 block per i) ---------------
// v7 (deferred W3 projection): T1[l] = sum_n W3[l,n] * Y[n] where
// Y[n] = sum_j fac_j*tanh(z_jn). The j-contraction commutes with the W3
// projection, so the per-body x2 round-trip (bf16 pack -> LDS -> stageB
// MFMA chain) is replaced by a register accumulator y2[8] += t. Removes
// per body: 8 cvt_pk, 4 DS writes, 2 DS b128 reads, 4 dependent-chain
// MFMAs; adds 8 pk_adds. W3 applied once in the tail (32 thr x 64 fma).
// Also strictly better numerics (one rounding of the sum, f32 accum).
__global__ __launch_bounds__(256) void pair_kernel(
    const float* __restrict__ ws, const unsigned short* __restrict__ wsu,
    float* __restrict__ out) {
    const int i    = blockIdx.x;
    const int tid  = threadIdx.x;
    const int w    = tid >> 6;
    const int lane = tid & 63;
    const int q    = lane >> 4;
    const int m    = lane & 15;
    const int jw   = w * 16;
    const int sub  = lane & 3;

    __shared__ unsigned short W2ls[64 * 72];
    __shared__ float redY[4][64];
    __shared__ float redU[4][32], redV[4][32];
    __shared__ float sfw[4];

    // ---- setup ----
    {
        int row = tid >> 2, c = (tid & 3) * 16;
        const uint4* s2 = (const uint4*)(wsu + U_W2B + row * 64 + c);
        uint4 d0 = s2[0], d1 = s2[1];
        uint4* dd = (uint4*)(&W2ls[row * 72 + c]);
        dd[0] = d0; dd[1] = d1;
    }

    v2f hi2[4];                     // own h pairs for fac
    {
        uint4 hv4 = *(const uint4*)(wsu + U_HJB + i * 32 + sub * 8);
        unsigned int hd[4] = {hv4.x, hv4.y, hv4.z, hv4.w};
        #pragma unroll
        for (int e = 0; e < 4; e++) { hi2[e].x = blo(hd[e]); hi2[e].y = bhi(hd[e]); }
    }
    f32x4 b2q[4];              // bias slice for MFMA C-init (unscaled)
    #pragma unroll
    for (int nb = 0; nb < 4; nb++) {
        float4 bv = *(const float4*)(ws + WS_BI2 + nb * 16 + q * 4);
        b2q[nb][0] = bv.x; b2q[nb][1] = bv.y; b2q[nb][2] = bv.z; b2q[nb][3] = bv.w;
    }
    // Ea = 2^(pre-scaled a_i): loop-invariant across all tiles, in registers
    v2f ea2[8];
    {
        const float* ap = ws + WS_AA + i * 64 + q * 8;
        #pragma unroll
        for (int s = 0; s < 2; s++) {
            float4 lo = *(const float4*)(ap + s * 32);
            float4 hi = *(const float4*)(ap + s * 32 + 4);
            ea2[s * 4 + 0].x = lo.x; ea2[s * 4 + 0].y = lo.y;
            ea2[s * 4 + 1].x = lo.z; ea2[s * 4 + 1].y = lo.w;
            ea2[s * 4 + 2].x = hi.x; ea2[s * 4 + 2].y = hi.y;
            ea2[s * 4 + 3].x = hi.z; ea2[s * 4 + 3].y = hi.w;
        }
    }
    v2f hiv2, ei2;             // (l=m, l=m+16) pairs for stage C
    hiv2.x = bf2f(wsu[U_HJB + i * 32 + m]);      hiv2.y = bf2f(wsu[U_HJB + i * 32 + 16 + m]);
    ei2.x = ws[WS_CI + i * 32 + m];              ei2.y = ws[WS_CI + i * 32 + 16 + m];
    const float aggi = ws[WS_AGG + i];
    const float sub0 = (sub == 0) ? 1.0f : 0.0f;

    // ---- streaming pointers + tile-0 prefetch ----
    const unsigned short* hp = wsu + U_HJB + (jw + (lane >> 2)) * 32 + sub * 8;
    const unsigned short* bp = wsu + U_BJB + (jw + m) * 64 + q * 8;
    const unsigned short* jp = wsu + U_JT + ((jw + q * 4) * 16 + m) * 8;

    uint4 hvA = *(const uint4*)hp;
    uint4 b0A = *(const uint4*)bp;
    uint4 b1A = *(const uint4*)(bp + 32);
    uint4 hvB, b0B, b1B;
    __syncthreads();

    // persistent accumulators: Y[n] partials (y2[nb*2+0]={e0,e1}, [nb*2+1]={e2,e3})
    v2f y2[8];
    #pragma unroll
    for (int k = 0; k < 8; k++) { y2[k].x = 0.f; y2[k].y = 0.f; }
    v2f u2; u2.x = 0.f; u2.y = 0.f;
    v2f vv2; vv2.x = 0.f; vv2.y = 0.f;
    float sumfac = 0.f;

    auto body = [&](int T, const uint4& hvc, const uint4& b0c, const uint4& b1c,
                    uint4& hvn, uint4& b0n, uint4& b1n) {
        // prefetch next tile's h/b
        hp += 2048; bp += 4096;
        hvn = *(const uint4*)hp;
        b0n = *(const uint4*)bp;
        b1n = *(const uint4*)(bp + 32);

        // jt loads for CURRENT tile (consumed in stage C)
        uint4 jt4[4];
        #pragma unroll
        for (int r = 0; r < 4; r++) jt4[r] = *(const uint4*)(jp + r * 128);
        jp += 8192;

        // 1) fac (lane owns j = T*64 + jw + (lane>>2)); zeroed at j==i
        float facm;
        {
            unsigned int hd[4] = {hvc.x, hvc.y, hvc.z, hvc.w};
            v2f s2v; s2v.x = 0.f; s2v.y = 0.f;
            #pragma unroll
            for (int e = 0; e < 4; e++) {
                v2f hj; hj.x = blo(hd[e]); hj.y = bhi(hd[e]);
                v2f d = hi2[e] - hj;
                s2v += d * d;                      // v_pk_fma
            }
            float s = s2v.x + s2v.y;
            s += __shfl_xor(s, 1); s += __shfl_xor(s, 2);
            int jj = T * 64 + jw + (lane >> 2);
            float facown = fminf(__builtin_amdgcn_rsqf(s), 2.0f) * aggi;
            facown = (jj == i) ? 0.0f : facown;
            sumfac = fmaf(sub0, facown, sumfac);
            facm = __shfl(facown, 4 * m);
        }

        // 2) x1 B-fragments: factored tanh (pk fma + 2 rcp, no exp2)
        bf16x8 afr[2];
        {
            unsigned int bd[8] = {b0c.x, b0c.y, b0c.z, b0c.w, b1c.x, b1c.y, b1c.z, b1c.w};
            #pragma unroll
            for (int s = 0; s < 2; s++) {
                union { uint4 u4; bf16x8 v; } pkd;
                #pragma unroll
                for (int e = 0; e < 4; e++) {
                    unsigned int bw = bd[s * 4 + e];
                    v2f eb; eb.x = blo(bw); eb.y = bhi(bw);
                    v2f t2 = tanh2_fact(ea2[s * 4 + e], eb);
                    ((unsigned int*)&pkd.u4)[e] = pk2(t2.x, t2.y);
                }
                afr[s] = pkd.v;
            }
        }

        // 3) stage A: X2^T = Wi2' * X1^T, C-init = bias (unscaled logit out)
        f32x4 accA[4];
        #pragma unroll
        for (int nb = 0; nb < 4; nb++) {
            f32x4 acc = b2q[nb];
            #pragma unroll
            for (int s = 0; s < 2; s++) {
                bf16x8 w2f = *(const bf16x8*)(&W2ls[(nb * 16 + m) * 72 + s * 32 + q * 8]);
                acc = __builtin_amdgcn_mfma_f32_16x16x32_bf16(w2f, afr[s], acc, 0, 0, 0);
            }
            accA[nb] = acc;
        }
        // epilogue A: Y[n] += facm * tanh(z), Pade(15,6), f32 register accum
        // (deferred W3 projection -- no pack, no LDS, no stageB MFMA)
        #pragma unroll
        for (int nb = 0; nb < 4; nb++) {
            v2f zA; zA.x = accA[nb][0]; zA.y = accA[nb][1];
            v2f zB; zB.x = accA[nb][2]; zB.y = accA[nb][3];
            v2f zzA = zA * zA, zzB = zB * zB;
            v2f nA = zA * (zzA + 15.0f), nB = zB * (zzB + 15.0f);
            v2f dA = zzA * 6.0f + 15.0f, dB = zzB * 6.0f + 15.0f;
            v2f rA, rB;
            rA.x = fast_rcp(dA.x); rA.y = fast_rcp(dA.y);
            rB.x = fast_rcp(dB.x); rB.y = fast_rcp(dB.y);
            y2[nb * 2 + 0] += nA * (rA * facm);
            y2[nb * 2 + 1] += nB * (rB * facm);
        }

        // 5) stage C: quantum partials; coh = rcp(1 + Ei*Ej), per-elem rcp
        #pragma unroll
        for (int r = 0; r < 4; r++) {
            uint4 jv = jt4[r];
            v2f hj2; hj2.x = blo(jv.x); hj2.y = bhi(jv.x);
            v2f ej2; ej2.x = blo(jv.y); ej2.y = bhi(jv.y);
            v2f pc2; pc2.x = blo(jv.z); pc2.y = bhi(jv.z);
            v2f ps2; ps2.x = blo(jv.w); ps2.y = bhi(jv.w);
            v2f dd = ei2 * ej2 + 1.0f;
            v2f coh; coh.x = fast_rcp(dd.x); coh.y = fast_rcp(dd.y);
            v2f cd = coh * (hiv2 - hj2);
            u2  += cd * pc2;
            vv2 += cd * ps2;
        }
    };

    #pragma unroll 1
    for (int T = 0; T < 16; T += 2) {
        body(T,     hvA, b0A, b1A, hvB, b0B, b1B);
        body(T + 1, hvB, b0B, b1B, hvA, b0A, b1A);
    }

    // ---- final reductions ----
    // Y over the 16 m-lanes (lane bits 0..3); every lane in a q-group ends
    // with the full Y for its n-set {nb*16 + q*4 + e}.
    float yv[16];
    #pragma unroll
    for (int nb = 0; nb < 4; nb++) {
        yv[nb * 4 + 0] = y2[nb * 2 + 0].x; yv[nb * 4 + 1] = y2[nb * 2 + 0].y;
        yv[nb * 4 + 2] = y2[nb * 2 + 1].x; yv[nb * 4 + 3] = y2[nb * 2 + 1].y;
    }
    #pragma unroll
    for (int k = 0; k < 16; k++) {
        yv[k] += __shfl_xor(yv[k], 1); yv[k] += __shfl_xor(yv[k], 2);
        yv[k] += __shfl_xor(yv[k], 4); yv[k] += __shfl_xor(yv[k], 8);
    }
    if (m == 0) {
        #pragma unroll
        for (int nb = 0; nb < 4; nb++) {
            #pragma unroll
            for (int e = 0; e < 4; e++)
                redY[w][nb * 16 + q * 4 + e] = yv[nb * 4 + e];
        }
    }
    float aU[2] = {u2.x, u2.y};
    float aV[2] = {vv2.x, vv2.y};
    #pragma unroll
    for (int lb = 0; lb < 2; lb++) {
        aU[lb] += __shfl_xor(aU[lb], 16); aU[lb] += __shfl_xor(aU[lb], 32);
        aV[lb] += __shfl_xor(aV[lb], 16); aV[lb] += __shfl_xor(aV[lb], 32);
    }
    sumfac += __shfl_xor(sumfac, 1);  sumfac += __shfl_xor(sumfac, 2);
    sumfac += __shfl_xor(sumfac, 4);  sumfac += __shfl_xor(sumfac, 8);
    sumfac += __shfl_xor(sumfac, 16); sumfac += __shfl_xor(sumfac, 32);
    if (lane < 16) {
        redU[w][m] = aU[0];      redU[w][16 + m] = aU[1];
        redV[w][m] = aV[0];      redV[w][16 + m] = aV[1];
    }
    if (lane == 0) sfw[w] = sumfac;
    __syncthreads();
    // combine Y across waves (64 threads, one n each)
    if (tid < 64) {
        redY[0][tid] = (redY[0][tid] + redY[1][tid]) + (redY[2][tid] + redY[3][tid]);
    }
    __syncthreads();
    if (tid < 32) {
        int l = tid;
        // T1[l] = sum_n W3[l,n] * Y[n]  (one-time 64-fma matvec)
        float t1 = 0.f;
        const uint4* w3p = (const uint4*)(wsu + U_W3B + l * 64);
        #pragma unroll
        for (int c = 0; c < 8; c++) {
            uint4 wv = w3p[c];
            unsigned int wd[4] = {wv.x, wv.y, wv.z, wv.w};
            const float* yp = &redY[0][c * 8];
            #pragma unroll
            for (int e = 0; e < 4; e++) {
                t1 = fmaf(blo(wd[e]), yp[2 * e],     t1);
                t1 = fmaf(bhi(wd[e]), yp[2 * e + 1], t1);
            }
        }
        float uu = (redU[0][l] + redU[1][l]) + (redU[2][l] + redU[3][l]);
        float vvv = (redV[0][l] + redV[1][l]) + (redV[2][l] + redV[3][l]);
        float sf = (sfw[0] + sfw[1]) + (sfw[2] + sfw[3]);
        int mm = l & 15;
        uint2 jti = *(const uint2*)(wsu + U_JT + (i * 16 + mm) * 8 + 4);  // cc/sc pair words
        float pic = (l < 16) ? blo(jti.x) : bhi(jti.x);
        float pis = (l < 16) ? blo(jti.y) : bhi(jti.y);
        float isum = t1 + sf * ws[WS_BI3 + l] - (pic * uu + pis * vvv);
        out[i * 33 + l] = 0.5f * ws[WS_SELF + i * 32 + l] + 0.3f * isum;
        // parallel |isum| tail reduce
        float ab = fabsf(isum);
        ab += __shfl_xor(ab, 1); ab += __shfl_xor(ab, 2);
        ab += __shfl_xor(ab, 4); ab += __shfl_xor(ab, 8);
        ab += __shfl_xor(ab, 16);
        if (tid == 0) out[i * 33 + 32] = 0.1f + 0.05f * ab;
    }
}

extern "C" void kernel_launch(void* const* d_in, const int* in_sizes, int n_in,
                              void* d_out, int out_size, void* d_ws, size_t ws_size,
                              hipStream_t stream) {
    const float* state   = (const float*)d_in[0];
    const float* Ws1     = (const float*)d_in[1];
    const float* bs1     = (const float*)d_in[2];
    const float* Ws2     = (const float*)d_in[3];
    const float* bs2     = (const float*)d_in[4];
    const float* Ws3     = (const float*)d_in[5];
    const float* bs3     = (const float*)d_in[6];
    const float* Wi1     = (const float*)d_in[7];
    const float* bi1     = (const float*)d_in[8];
    const float* Wi2     = (const float*)d_in[9];
    const float* bi2     = (const float*)d_in[10];
    const float* Wi3     = (const float*)d_in[11];
    const float* bi3     = (const float*)d_in[12];
    const float* phase_w = (const float*)d_in[13];
    const float* Wc      = (const float*)d_in[14];
    const float* bc      = (const float*)d_in[15];
    const float* aggr    = (const float*)d_in[16];

    float* ws = (float*)d_ws;
    unsigned short* wsu = (unsigned short*)(ws + WS_FEND);
    float* out = (float*)d_out;

    precompute<<<256, 256, 0, stream>>>(state, Ws1, bs1, Ws2, bs2, Ws3, bs3,
                                        Wi1, bi1, Wi2, bi2, Wi3, bi3,
                                        phase_w, Wc, bc, aggr, ws, wsu);
    pair_kernel<<<NN, 256, 0, stream>>>(ws, wsu, out);
}

// Round 8
// 138.128 us; speedup vs baseline: 1.0295x; 1.0031x over previous
//
#include <hip/hip_runtime.h>
#include <hip/hip_bf16.h>
#include <math.h>

#define NN 1024
#define LDIM 32
#define HDIM 64

// ---------------- fp32 workspace layout (float offsets) ----------------
#define WS_SELF 0                        // N*L   self_term [i][l]
#define WS_AA   (WS_SELF + NN*LDIM)      // N*H   Ea = 2^(2log2e * a_i) [i][h]
#define WS_CI   (WS_AA   + NN*HDIM)      // N*L   Ei = 2^(-log2e*(ci+bc)) [i][l]
#define WS_AGG  (WS_CI   + NN*LDIM)      // N     sigmoid(aggr)
#define WS_BI2  (WS_AGG  + NN)           // H     bi2 (UNSCALED - Pade epilogue)
#define WS_BI3  (WS_BI2  + HDIM)         // L     bi3 (unscaled)
#define WS_FEND (WS_BI3  + LDIM)

// ---------------- bf16(u16) region (short offsets from wsu) -------------
#define U_BJB  0                         // N*H   Eb = 2^(2log2e * b_j) [j][h]
#define U_HJB  (U_BJB + NN*HDIM)         // N*L   h   [j][l]
#define U_JT   (U_HJB + NN*LDIM)         // N*16*8 paired {h0,h1}{Ej0,Ej1}{pc0,pc1}{ps0,ps1}
#define U_W2B  (U_JT  + NN*LDIM*4)       // H*H   Wi2 [n][k] (UNSCALED)
#define U_W3B  (U_W2B + HDIM*HDIM)       // L*H   Wi3 [l][k] (unscaled)
#define U_END  (U_W3B + LDIM*HDIM)

// packed-pair transposed weight tables in precompute LDS (uint offsets)
#define PK_W1  0        // 16*64   Ws1
#define PK_W2  1024     // 32*64   Ws2
#define PK_W3  3072     // 32*32   Ws3
#define PK_WI1 4096     // 64*64   Wi1
#define PK_WC  8192     // 32*32   Wc
#define PK_END 9216     // 36 KB

#define K2P  2.88539008f     // 2*log2(e)
#define K1N  (-1.44269504f)  // -log2(e)

typedef __attribute__((ext_vector_type(8))) short bf16x8;
typedef __attribute__((ext_vector_type(4))) float f32x4;
typedef __attribute__((ext_vector_type(2))) float v2f;

__device__ __forceinline__ float fast_rcp(float x) { return __builtin_amdgcn_rcpf(x); }
__device__ __forceinline__ float fast_tanh(float x) {          // full version (precompute)
    float e = __builtin_amdgcn_exp2f(x * K2P);
    return 1.0f - 2.0f * fast_rcp(e + 1.0f);
}
__device__ __forceinline__ float fast_sigmoid(float x) {       // full version (precompute)
    return fast_rcp(1.0f + __builtin_amdgcn_exp2f(x * K1N));
}
__device__ __forceinline__ float blo(unsigned int u) { union { unsigned int i; float f; } v; v.i = u << 16; return v.f; }
__device__ __forceinline__ float bhi(unsigned int u) { union { unsigned int i; float f; } v; v.i = u & 0xffff0000u; return v.f; }
__device__ __forceinline__ float bf2f(unsigned short u) { union { unsigned int i; float f; } v; v.i = ((unsigned int)u) << 16; return v.f; }
__device__ __forceinline__ unsigned short f2bf(float f) {
    __hip_bfloat16 b = __float2bfloat16(f);
    unsigned short u; __builtin_memcpy(&u, &b, 2); return u;
}
__device__ __forceinline__ unsigned int pk2(float a, float b) {
    float2 t; t.x = a; t.y = b;
    __hip_bfloat162 h = __float22bfloat162_rn(t);
    unsigned int u; __builtin_memcpy(&u, &h, 4); return u;
}

// --- forced VOP3P packed-f32 (dual-issue) via inline asm -----------------
// hipcc often scalarizes ext_vector f32 math into 2 VALU ops; these pin
// the packed forms. Pure-ALU asm: deps tracked via operands, no hazards.
__device__ __forceinline__ v2f pk_fma(v2f a, v2f b, v2f c) {
    v2f d; asm("v_pk_fma_f32 %0, %1, %2, %3" : "=v"(d) : "v"(a), "v"(b), "v"(c)); return d;
}
__device__ __forceinline__ v2f pk_mul(v2f a, v2f b) {
    v2f d; asm("v_pk_mul_f32 %0, %1, %2" : "=v"(d) : "v"(a), "v"(b)); return d;
}
__device__ __forceinline__ v2f pk_add(v2f a, v2f b) {
    v2f d; asm("v_pk_add_f32 %0, %1, %2" : "=v"(d) : "v"(a), "v"(b)); return d;
}
__device__ __forceinline__ v2f pk_sub(v2f a, v2f b) {          // a - b
    v2f d; asm("v_pk_add_f32 %0, %1, %2 neg_lo:[0,1] neg_hi:[0,1]" : "=v"(d) : "v"(a), "v"(b)); return d;
}
__device__ __forceinline__ v2f pk_fma_nb(v2f a, v2f b, v2f c) { // a*(-b) + c
    v2f d; asm("v_pk_fma_f32 %0, %1, %2, %3 neg_lo:[0,1,0] neg_hi:[0,1,0]" : "=v"(d) : "v"(a), "v"(b), "v"(c)); return d;
}
__device__ __forceinline__ v2f splat2(float x) { v2f r; r.x = x; r.y = x; return r; }

// ------------- kernel 1: precompute (weights packed in-block) -------------
__global__ __launch_bounds__(256) void precompute(
    const float* __restrict__ state,
    const float* __restrict__ Ws1, const float* __restrict__ bs1,
    const float* __restrict__ Ws2, const float* __restrict__ bs2,
    const float* __restrict__ Ws3, const float* __restrict__ bs3,
    const float* __restrict__ Wi1, const float* __restrict__ bi1,
    const float* __restrict__ Wi2, const float* __restrict__ bi2,
    const float* __restrict__ Wi3, const float* __restrict__ bi3,
    const float* __restrict__ phw, const float* __restrict__ Wc,
    const float* __restrict__ bc,  const float* __restrict__ aggr,
    float* __restrict__ ws, unsigned short* __restrict__ wsu) {
    const int tid = threadIdx.x;
    const int w = tid >> 6, t = tid & 63;
    const int i = blockIdx.x * 4 + w;

    __shared__ unsigned int wlds[PK_END];
    __shared__ float shh[4][32], shdh[4][32], sht1[4][64], sht2[4][64];
    __shared__ float shph[4];

    {
        const float2* s1 = (const float2*)Ws1;
        #pragma unroll
        for (int r = 0; r < 4; r++) { int e = tid + r * 256; int f = e >> 4, k2 = e & 15;
            float2 v = s1[e]; wlds[PK_W1 + k2 * 64 + f] = pk2(v.x, v.y); }
        const float2* s2 = (const float2*)Ws2;
        #pragma unroll
        for (int r = 0; r < 8; r++) { int e = tid + r * 256; int f = e >> 5, k2 = e & 31;
            float2 v = s2[e]; wlds[PK_W2 + k2 * 64 + f] = pk2(v.x, v.y); }
        const float2* s3 = (const float2*)Ws3;
        #pragma unroll
        for (int r = 0; r < 4; r++) { int e = tid + r * 256; int f = e >> 5, k2 = e & 31;
            float2 v = s3[e]; wlds[PK_W3 + k2 * 32 + f] = pk2(v.x, v.y); }
        const float2* si = (const float2*)Wi1;
        #pragma unroll
        for (int r = 0; r < 16; r++) { int e = tid + r * 256; int f = e >> 6, c2 = e & 63;
            float2 v = si[e]; wlds[PK_WI1 + c2 * 64 + f] = pk2(v.x, v.y); }
        const float2* sc = (const float2*)Wc;
        #pragma unroll
        for (int r = 0; r < 4; r++) { int e = tid + r * 256; int f = e >> 5, c2 = e & 31;
            float2 v = sc[e]; wlds[PK_WC + c2 * 32 + f] = pk2(v.x, v.y); }
    }
    if (blockIdx.x == 0) {
        // Wi2/bi2 UNSCALED: pair epilogue uses Pade tanh, not exp2
        #pragma unroll
        for (int r = 0; r < 16; r++) { int e = tid + r * 256; wsu[U_W2B + e] = f2bf(Wi2[e]); }
        #pragma unroll
        for (int r = 0; r < 8; r++)  { int e = tid + r * 256; wsu[U_W3B + e] = f2bf(Wi3[e]); }
        if (tid < HDIM) ws[WS_BI2 + tid] = bi2[tid];
        if (tid < LDIM) ws[WS_BI3 + tid] = bi3[tid];
    }

    float sv = (t < 33) ? state[i * 33 + t] : 0.f;
    if (t < 32) shh[w][t] = sv;
    if (t == 32) shph[w] = sv;
    if (t == 33) ws[WS_AGG + i] = fast_sigmoid(aggr[i]);
    __syncthreads();

    {
        float s = bs1[t];
        const unsigned int* W = wlds + PK_W1;
        #pragma unroll
        for (int k2 = 0; k2 < 16; k2++) {
            unsigned int p = W[k2 * 64 + t];
            s = fmaf(blo(p), shh[w][2 * k2], s);
            s = fmaf(bhi(p), shh[w][2 * k2 + 1], s);
        }
        sht1[w][t] = fast_tanh(s);
    }
    __syncthreads();
    {
        float s = bs2[t];
        const unsigned int* W = wlds + PK_W2;
        #pragma unroll
        for (int k2 = 0; k2 < 32; k2++) {
            unsigned int p = W[k2 * 64 + t];
            s = fmaf(blo(p), sht1[w][2 * k2], s);
            s = fmaf(bhi(p), sht1[w][2 * k2 + 1], s);
        }
        sht2[w][t] = fast_tanh(s);
    }
    __syncthreads();
    if (t < 32) {
        float s = bs3[t];
        const unsigned int* W = wlds + PK_W3;
        #pragma unroll
        for (int k2 = 0; k2 < 32; k2++) {
            unsigned int p = W[k2 * 32 + t];
            s = fmaf(blo(p), sht2[w][2 * k2], s);
            s = fmaf(bhi(p), sht2[w][2 * k2 + 1], s);
        }
        ws[WS_SELF + i * 32 + t] = s;
        shdh[w][t] = s;
    }
    __syncthreads();
    {
        float sa = 0.f, sb = bi1[t];
        const unsigned int* W = wlds + PK_WI1;
        #pragma unroll
        for (int k2 = 0; k2 < 16; k2++) {
            float h0 = shh[w][2 * k2], h1 = shh[w][2 * k2 + 1];
            float d0 = shdh[w][2 * k2], d1 = shdh[w][2 * k2 + 1];
            unsigned int wa  = W[k2 * 64 + t];
            unsigned int wb  = W[(16 + k2) * 64 + t];
            unsigned int wa2 = W[(32 + k2) * 64 + t];
            unsigned int wb2 = W[(48 + k2) * 64 + t];
            sa = fmaf(blo(wa), h0, sa);  sa = fmaf(bhi(wa), h1, sa);
            sb = fmaf(blo(wb), h0, sb);  sb = fmaf(bhi(wb), h1, sb);
            sa = fmaf(blo(wa2), d0, sa); sa = fmaf(bhi(wa2), d1, sa);
            sb = fmaf(blo(wb2), d0, sb); sb = fmaf(bhi(wb2), d1, sb);
        }
        // exp-factorized: store E = 2^(pre-scaled logit) instead of logit
        ws[WS_AA + i * 64 + t]  = __builtin_amdgcn_exp2f(sa * K2P);
        wsu[U_BJB + i * 64 + t] = f2bf(__builtin_amdgcn_exp2f(sb * K2P));
    }
    if (t < 32) {
        float si2 = 0.f, sj = 0.f;
        const unsigned int* W = wlds + PK_WC;
        #pragma unroll
        for (int m2 = 0; m2 < 16; m2++) {
            float h0 = shh[w][2 * m2], h1 = shh[w][2 * m2 + 1];
            unsigned int wi = W[m2 * 32 + t];
            unsigned int wj = W[(16 + m2) * 32 + t];
            si2 = fmaf(blo(wi), h0, si2); si2 = fmaf(bhi(wi), h1, si2);
            sj  = fmaf(blo(wj), h0, sj);  sj  = fmaf(bhi(wj), h1, sj);
        }
        // Ei = 2^(-log2e*(ci+bc)); sigmoid(ci+cj) = rcp(1 + Ei*Ej)
        ws[WS_CI + i * 32 + t] = __builtin_amdgcn_exp2f((si2 + bc[t]) * K1N);
        float h = shh[w][t];
        wsu[U_HJB + i * 32 + t] = f2bf(h);
        float ejn = __builtin_amdgcn_exp2f(sj * K1N);
        float sc_, cc_;
        __sincosf(shph[w] * phw[t], &sc_, &cc_);
        // pair (l, l+16) into one bf16 uint4 for stage-C pk math
        int p = (t & 15) + 16;                       // partner lane (self for t>=16)
        float h_p  = __shfl(h,   p);
        float e_p  = __shfl(ejn, p);
        float cc_p = __shfl(cc_, p);
        float sc_p = __shfl(sc_, p);
        if (t < 16) {
            uint4 o; o.x = pk2(h, h_p); o.y = pk2(ejn, e_p);
            o.z = pk2(cc_, cc_p); o.w = pk2(sc_, sc_p);
            *(uint4*)(wsu + U_JT + (i * 16 + t) * 8) = o;
        }
    }
}

// ------------- kernel 2: MFMA pairwise core (1 block per i) ---------------
// v8 (forced VOP3P): hand count predicts VALUBusy ~35%, measured 64% ->
// ~2x instruction bloat, consistent with hipcc scalarizing v2f math.
// All hot v2f chains (fac dist2, x1 tanh, Pade epilogue, stage-C
// sigmoid/accum) now pinned to v_pk_{fma,mul,add}_f32 via inline asm
// (sub and 1-2r via neg_lo/neg_hi). Constants {1,2,6,15} splatted in
// registers (+8 VGPR); bias b2q moved to LDS (-16 VGPR) to stay under
// the 128-VGPR occupancy cliff.
__global__ __launch_bounds__(256) void pair_kernel(
    const float* __restrict__ ws, const unsigned short* __restrict__ wsu,
    float* __restrict__ out) {
    const int i    = blockIdx.x;
    const int tid  = threadIdx.x;
    const int w    = tid >> 6;
    const int lane = tid & 63;
    const int q    = lane >> 4;
    const int m    = lane & 15;
    const int jw   = w * 16;
    const int sub  = lane & 3;

    __shared__ unsigned short W2ls[64 * 72];
    __shared__ float bi2ls[64];
    __shared__ float redY[4][64];
    __shared__ float redU[4][32], redV[4][32];
    __shared__ float sfw[4];

    // ---- setup ----
    {
        int row = tid >> 2, c = (tid & 3) * 16;
        const uint4* s2 = (const uint4*)(wsu + U_W2B + row * 64 + c);
        uint4 d0 = s2[0], d1 = s2[1];
        uint4* dd = (uint4*)(&W2ls[row * 72 + c]);
        dd[0] = d0; dd[1] = d1;
    }
    if (tid < 64) bi2ls[tid] = ws[WS_BI2 + tid];

    v2f hi2[4];                     // own h pairs for fac
    {
        uint4 hv4 = *(const uint4*)(wsu + U_HJB + i * 32 + sub * 8);
        unsigned int hd[4] = {hv4.x, hv4.y, hv4.z, hv4.w};
        #pragma unroll
        for (int e = 0; e < 4; e++) { hi2[e].x = blo(hd[e]); hi2[e].y = bhi(hd[e]); }
    }
    // Ea = 2^(pre-scaled a_i): loop-invariant across all tiles, in registers
    v2f ea2[8];
    {
        const float* ap = ws + WS_AA + i * 64 + q * 8;
        #pragma unroll
        for (int s = 0; s < 2; s++) {
            float4 lo = *(const float4*)(ap + s * 32);
            float4 hi = *(const float4*)(ap + s * 32 + 4);
            ea2[s * 4 + 0].x = lo.x; ea2[s * 4 + 0].y = lo.y;
            ea2[s * 4 + 1].x = lo.z; ea2[s * 4 + 1].y = lo.w;
            ea2[s * 4 + 2].x = hi.x; ea2[s * 4 + 2].y = hi.y;
            ea2[s * 4 + 3].x = hi.z; ea2[s * 4 + 3].y = hi.w;
        }
    }
    v2f hiv2, ei2;             // (l=m, l=m+16) pairs for stage C
    hiv2.x = bf2f(wsu[U_HJB + i * 32 + m]);      hiv2.y = bf2f(wsu[U_HJB + i * 32 + 16 + m]);
    ei2.x = ws[WS_CI + i * 32 + m];              ei2.y = ws[WS_CI + i * 32 + 16 + m];
    const float aggi = ws[WS_AGG + i];
    const float sub0 = (sub == 0) ? 1.0f : 0.0f;

    // packed constants for the asm VOP3P ops
    const v2f c_one = splat2(1.0f);
    const v2f c_two = splat2(2.0f);
    const v2f c_six = splat2(6.0f);
    const v2f c_f15 = splat2(15.0f);

    // ---- streaming pointers + tile-0 prefetch ----
    const unsigned short* hp = wsu + U_HJB + (jw + (lane >> 2)) * 32 + sub * 8;
    const unsigned short* bp = wsu + U_BJB + (jw + m) * 64 + q * 8;
    const unsigned short* jp = wsu + U_JT + ((jw + q * 4) * 16 + m) * 8;

    uint4 hvA = *(const uint4*)hp;
    uint4 b0A = *(const uint4*)bp;
    uint4 b1A = *(const uint4*)(bp + 32);
    uint4 hvB, b0B, b1B;
    __syncthreads();

    // persistent accumulators: Y[n] partials
    v2f y2[8];
    #pragma unroll
    for (int k = 0; k < 8; k++) { y2[k].x = 0.f; y2[k].y = 0.f; }
    v2f u2; u2.x = 0.f; u2.y = 0.f;
    v2f vv2; vv2.x = 0.f; vv2.y = 0.f;
    float sumfac = 0.f;

    auto body = [&](int T, const uint4& hvc, const uint4& b0c, const uint4& b1c,
                    uint4& hvn, uint4& b0n, uint4& b1n) {
        // prefetch next tile's h/b
        hp += 2048; bp += 4096;
        hvn = *(const uint4*)hp;
        b0n = *(const uint4*)bp;
        b1n = *(const uint4*)(bp + 32);

        // jt loads for CURRENT tile (consumed in stage C)
        uint4 jt4[4];
        #pragma unroll
        for (int r = 0; r < 4; r++) jt4[r] = *(const uint4*)(jp + r * 128);
        jp += 8192;

        // 1) fac (lane owns j = T*64 + jw + (lane>>2)); zeroed at j==i
        float facm;
        {
            unsigned int hd[4] = {hvc.x, hvc.y, hvc.z, hvc.w};
            v2f hj0; hj0.x = blo(hd[0]); hj0.y = bhi(hd[0]);
            v2f d0 = pk_sub(hi2[0], hj0);
            v2f s2v = pk_mul(d0, d0);
            #pragma unroll
            for (int e = 1; e < 4; e++) {
                v2f hj; hj.x = blo(hd[e]); hj.y = bhi(hd[e]);
                v2f d = pk_sub(hi2[e], hj);
                s2v = pk_fma(d, d, s2v);
            }
            float s = s2v.x + s2v.y;
            s += __shfl_xor(s, 1); s += __shfl_xor(s, 2);
            int jj = T * 64 + jw + (lane >> 2);
            float facown = fminf(__builtin_amdgcn_rsqf(s), 2.0f) * aggi;
            facown = (jj == i) ? 0.0f : facown;
            sumfac = fmaf(sub0, facown, sumfac);
            facm = __shfl(facown, 4 * m);
        }
        const v2f fmv = splat2(facm);

        // 2) x1 B-fragments: factored tanh = 1 - 2*rcp(Ea*Eb + 1)
        bf16x8 afr[2];
        {
            unsigned int bd[8] = {b0c.x, b0c.y, b0c.z, b0c.w, b1c.x, b1c.y, b1c.z, b1c.w};
            #pragma unroll
            for (int s = 0; s < 2; s++) {
                union { uint4 u4; bf16x8 v; } pkd;
                #pragma unroll
                for (int e = 0; e < 4; e++) {
                    unsigned int bw = bd[s * 4 + e];
                    v2f eb; eb.x = blo(bw); eb.y = bhi(bw);
                    v2f d = pk_fma(ea2[s * 4 + e], eb, c_one);
                    v2f r; r.x = fast_rcp(d.x); r.y = fast_rcp(d.y);
                    v2f t2 = pk_fma_nb(r, c_two, c_one);   // 1 - 2r
                    ((unsigned int*)&pkd.u4)[e] = pk2(t2.x, t2.y);
                }
                afr[s] = pkd.v;
            }
        }

        // 3) stage A: X2^T = Wi2' * X1^T, C-init = bias (from LDS)
        f32x4 accA[4];
        #pragma unroll
        for (int nb = 0; nb < 4; nb++) {
            float4 bv = *(const float4*)(&bi2ls[nb * 16 + q * 4]);
            f32x4 acc; acc[0] = bv.x; acc[1] = bv.y; acc[2] = bv.z; acc[3] = bv.w;
            #pragma unroll
            for (int s = 0; s < 2; s++) {
                bf16x8 w2f = *(const bf16x8*)(&W2ls[(nb * 16 + m) * 72 + s * 32 + q * 8]);
                acc = __builtin_amdgcn_mfma_f32_16x16x32_bf16(w2f, afr[s], acc, 0, 0, 0);
            }
            accA[nb] = acc;
        }
        // epilogue A: Y[n] += facm * tanh(z), Pade(15,6), packed f32
        #pragma unroll
        for (int nb = 0; nb < 4; nb++) {
            v2f zA; zA.x = accA[nb][0]; zA.y = accA[nb][1];
            v2f zB; zB.x = accA[nb][2]; zB.y = accA[nb][3];
            v2f zzA = pk_mul(zA, zA), zzB = pk_mul(zB, zB);
            v2f nA = pk_mul(zA, pk_add(zzA, c_f15));
            v2f nB = pk_mul(zB, pk_add(zzB, c_f15));
            v2f dA = pk_fma(zzA, c_six, c_f15);
            v2f dB = pk_fma(zzB, c_six, c_f15);
            v2f rA, rB;
            rA.x = fast_rcp(dA.x); rA.y = fast_rcp(dA.y);
            rB.x = fast_rcp(dB.x); rB.y = fast_rcp(dB.y);
            v2f rfA = pk_mul(rA, fmv), rfB = pk_mul(rB, fmv);
            y2[nb * 2 + 0] = pk_fma(nA, rfA, y2[nb * 2 + 0]);
            y2[nb * 2 + 1] = pk_fma(nB, rfB, y2[nb * 2 + 1]);
        }

        // 5) stage C: quantum partials; coh = rcp(1 + Ei*Ej), packed f32
        #pragma unroll
        for (int r = 0; r < 4; r++) {
            uint4 jv = jt4[r];
            v2f hj2; hj2.x = blo(jv.x); hj2.y = bhi(jv.x);
            v2f ej2; ej2.x = blo(jv.y); ej2.y = bhi(jv.y);
            v2f pc2; pc2.x = blo(jv.z); pc2.y = bhi(jv.z);
            v2f ps2; ps2.x = blo(jv.w); ps2.y = bhi(jv.w);
            v2f dd = pk_fma(ei2, ej2, c_one);
            v2f coh; coh.x = fast_rcp(dd.x); coh.y = fast_rcp(dd.y);
            v2f cd = pk_mul(coh, pk_sub(hiv2, hj2));
            u2  = pk_fma(cd, pc2, u2);
            vv2 = pk_fma(cd, ps2, vv2);
        }
    };

    #pragma unroll 1
    for (int T = 0; T < 16; T += 2) {
        body(T,     hvA, b0A, b1A, hvB, b0B, b1B);
        body(T + 1, hvB, b0B, b1B, hvA, b0A, b1A);
    }

    // ---- final reductions ----
    float yv[16];
    #pragma unroll
    for (int nb = 0; nb < 4; nb++) {
        yv[nb * 4 + 0] = y2[nb * 2 + 0].x; yv[nb * 4 + 1] = y2[nb * 2 + 0].y;
        yv[nb * 4 + 2] = y2[nb * 2 + 1].x; yv[nb * 4 + 3] = y2[nb * 2 + 1].y;
    }
    #pragma unroll
    for (int k = 0; k < 16; k++) {
        yv[k] += __shfl_xor(yv[k], 1); yv[k] += __shfl_xor(yv[k], 2);
        yv[k] += __shfl_xor(yv[k], 4); yv[k] += __shfl_xor(yv[k], 8);
    }
    if (m == 0) {
        #pragma unroll
        for (int nb = 0; nb < 4; nb++) {
            #pragma unroll
            for (int e = 0; e < 4; e++)
                redY[w][nb * 16 + q * 4 + e] = yv[nb * 4 + e];
        }
    }
    float aU[2] = {u2.x, u2.y};
    float aV[2] = {vv2.x, vv2.y};
    #pragma unroll
    for (int lb = 0; lb < 2; lb++) {
        aU[lb] += __shfl_xor(aU[lb], 16); aU[lb] += __shfl_xor(aU[lb], 32);
        aV[lb] += __shfl_xor(aV[lb], 16); aV[lb] += __shfl_xor(aV[lb], 32);
    }
    sumfac += __shfl_xor(sumfac, 1);  sumfac += __shfl_xor(sumfac, 2);
    sumfac += __shfl_xor(sumfac, 4);  sumfac += __shfl_xor(sumfac, 8);
    sumfac += __shfl_xor(sumfac, 16); sumfac += __shfl_xor(sumfac, 32);
    if (lane < 16) {
        redU[w][m] = aU[0];      redU[w][16 + m] = aU[1];
        redV[w][m] = aV[0];      redV[w][16 + m] = aV[1];
    }
    if (lane == 0) sfw[w] = sumfac;
    __syncthreads();
    if (tid < 64) {
        redY[0][tid] = (redY[0][tid] + redY[1][tid]) + (redY[2][tid] + redY[3][tid]);
    }
    __syncthreads();
    if (tid < 32) {
        int l = tid;
        // T1[l] = sum_n W3[l,n] * Y[n]  (one-time 64-fma matvec)
        float t1 = 0.f;
        const uint4* w3p = (const uint4*)(wsu + U_W3B + l * 64);
        #pragma unroll
        for (int c = 0; c < 8; c++) {
            uint4 wv = w3p[c];
            unsigned int wd[4] = {wv.x, wv.y, wv.z, wv.w};
            const float* yp = &redY[0][c * 8];
            #pragma unroll
            for (int e = 0; e < 4; e++) {
                t1 = fmaf(blo(wd[e]), yp[2 * e],     t1);
                t1 = fmaf(bhi(wd[e]), yp[2 * e + 1], t1);
            }
        }
        float uu = (redU[0][l] + redU[1][l]) + (redU[2][l] + redU[3][l]);
        float vvv = (redV[0][l] + redV[1][l]) + (redV[2][l] + redV[3][l]);
        float sf = (sfw[0] + sfw[1]) + (sfw[2] + sfw[3]);
        int mm = l & 15;
        uint2 jti = *(const uint2*)(wsu + U_JT + (i * 16 + mm) * 8 + 4);  // cc/sc pair words
        float pic = (l < 16) ? blo(jti.x) : bhi(jti.x);
        float pis = (l < 16) ? blo(jti.y) : bhi(jti.y);
        float isum = t1 + sf * ws[WS_BI3 + l] - (pic * uu + pis * vvv);
        out[i * 33 + l] = 0.5f * ws[WS_SELF + i * 32 + l] + 0.3f * isum;
        // parallel |isum| tail reduce
        float ab = fabsf(isum);
        ab += __shfl_xor(ab, 1); ab += __shfl_xor(ab, 2);
        ab += __shfl_xor(ab, 4); ab += __shfl_xor(ab, 8);
        ab += __shfl_xor(ab, 16);
        if (tid == 0) out[i * 33 + 32] = 0.1f + 0.05f * ab;
    }
}

extern "C" void kernel_launch(void* const* d_in, const int* in_sizes, int n_in,
                              void* d_out, int out_size, void* d_ws, size_t ws_size,
                              hipStream_t stream) {
    const float* state   = (const float*)d_in[0];
    const float* Ws1     = (const float*)d_in[1];
    const float* bs1     = (const float*)d_in[2];
    const float* Ws2     = (const float*)d_in[3];
    const float* bs2     = (const float*)d_in[4];
    const float* Ws3     = (const float*)d_in[5];
    const float* bs3     = (const float*)d_in[6];
    const float* Wi1     = (const float*)d_in[7];
    const float* bi1     = (const float*)d_in[8];
    const float* Wi2     = (const float*)d_in[9];
    const float* bi2     = (const float*)d_in[10];
    const float* Wi3     = (const float*)d_in[11];
    const float* bi3     = (const float*)d_in[12];
    const float* phase_w = (const float*)d_in[13];
    const float* Wc      = (const float*)d_in[14];
    const float* bc      = (const float*)d_in[15];
    const float* aggr    = (const float*)d_in[16];

    float* ws = (float*)d_ws;
    unsigned short* wsu = (unsigned short*)(ws + WS_FEND);
    float* out = (float*)d_out;

    precompute<<<256, 256, 0, stream>>>(state, Ws1, bs1, Ws2, bs2, Ws3, bs3,
                                        Wi1, bi1, Wi2, bi2, Wi3, bi3,
                                        phase_w, Wc, bc, aggr, ws, wsu);
    pair_kernel<<<NN, 256, 0, stream>>>(ws, wsu, out);
}

// Round 9
// 134.911 us; speedup vs baseline: 1.0541x; 1.0238x over previous
//
#include <hip/hip_runtime.h>
#include <hip/hip_bf16.h>
#include <math.h>

#define NN 1024
#define LDIM 32
#define HDIM 64

// ---------------- fp32 workspace layout (float offsets) ----------------
#define WS_SELF 0                        // N*L   self_term [i][l]
#define WS_AA   (WS_SELF + NN*LDIM)      // N*H   Ea = 2^(2log2e * a_i) [i][h]
#define WS_CI   (WS_AA   + NN*HDIM)      // N*L   Ei = 2^(-log2e*(ci+bc)) [i][l]
#define WS_AGG  (WS_CI   + NN*LDIM)      // N     sigmoid(aggr)
#define WS_BI2  (WS_AGG  + NN)           // H     bi2 (UNSCALED - Pade epilogue)
#define WS_BI3  (WS_BI2  + HDIM)         // L     bi3 (unscaled)
#define WS_FEND (WS_BI3  + LDIM)

// ---------------- bf16(u16) region (short offsets from wsu) -------------
#define U_BJB  0                         // N*H   Eb = 2^(2log2e * b_j) [j][h]
#define U_HJB  (U_BJB + NN*HDIM)         // N*L   h   [j][l]
#define U_JT   (U_HJB + NN*LDIM)         // N*16*8 paired {h0,h1}{Ej0,Ej1}{pc0,pc1}{ps0,ps1}
#define U_W2B  (U_HJB + NN*LDIM + NN*LDIM*4)  // H*H   Wi2 [n][k] (UNSCALED)
#define U_W3B  (U_W2B + HDIM*HDIM)       // L*H   Wi3 [l][k] (unscaled)
#define U_END  (U_W3B + LDIM*HDIM)

// packed-pair transposed weight tables in precompute LDS (uint offsets)
#define PK_W1  0        // 16*64   Ws1
#define PK_W2  1024     // 32*64   Ws2
#define PK_W3  3072     // 32*32   Ws3
#define PK_WI1 4096     // 64*64   Wi1
#define PK_WC  8192     // 32*32   Wc
#define PK_END 9216     // 36 KB

#define K2P  2.88539008f     // 2*log2(e)
#define K1N  (-1.44269504f)  // -log2(e)

typedef __attribute__((ext_vector_type(8))) short bf16x8;
typedef __attribute__((ext_vector_type(4))) float f32x4;
typedef __attribute__((ext_vector_type(2))) float v2f;

__device__ __forceinline__ float fast_rcp(float x) { return __builtin_amdgcn_rcpf(x); }
__device__ __forceinline__ float fast_tanh(float x) {          // full version (precompute)
    float e = __builtin_amdgcn_exp2f(x * K2P);
    return 1.0f - 2.0f * fast_rcp(e + 1.0f);
}
__device__ __forceinline__ float fast_sigmoid(float x) {       // full version (precompute)
    return fast_rcp(1.0f + __builtin_amdgcn_exp2f(x * K1N));
}
__device__ __forceinline__ float blo(unsigned int u) { union { unsigned int i; float f; } v; v.i = u << 16; return v.f; }
__device__ __forceinline__ float bhi(unsigned int u) { union { unsigned int i; float f; } v; v.i = u & 0xffff0000u; return v.f; }
__device__ __forceinline__ float bf2f(unsigned short u) { union { unsigned int i; float f; } v; v.i = ((unsigned int)u) << 16; return v.f; }
__device__ __forceinline__ unsigned short f2bf(float f) {
    __hip_bfloat16 b = __float2bfloat16(f);
    unsigned short u; __builtin_memcpy(&u, &b, 2); return u;
}
__device__ __forceinline__ unsigned int pk2(float a, float b) {
    float2 t; t.x = a; t.y = b;
    __hip_bfloat162 h = __float22bfloat162_rn(t);
    unsigned int u; __builtin_memcpy(&u, &h, 4); return u;
}

// factored tanh (exp-factorized, no exp2 in loop)
__device__ __forceinline__ v2f tanh2_fact(v2f ea, v2f eb) {
    v2f d = ea * eb + 1.0f;
    v2f r; r.x = fast_rcp(d.x); r.y = fast_rcp(d.y);
    return 1.0f - 2.0f * r;
}

// ------------- kernel 1: precompute (weights packed in-block) -------------
__global__ __launch_bounds__(256) void precompute(
    const float* __restrict__ state,
    const float* __restrict__ Ws1, const float* __restrict__ bs1,
    const float* __restrict__ Ws2, const float* __restrict__ bs2,
    const float* __restrict__ Ws3, const float* __restrict__ bs3,
    const float* __restrict__ Wi1, const float* __restrict__ bi1,
    const float* __restrict__ Wi2, const float* __restrict__ bi2,
    const float* __restrict__ Wi3, const float* __restrict__ bi3,
    const float* __restrict__ phw, const float* __restrict__ Wc,
    const float* __restrict__ bc,  const float* __restrict__ aggr,
    float* __restrict__ ws, unsigned short* __restrict__ wsu) {
    const int tid = threadIdx.x;
    const int w = tid >> 6, t = tid & 63;
    const int i = blockIdx.x * 4 + w;

    __shared__ unsigned int wlds[PK_END];
    __shared__ float shh[4][32], shdh[4][32], sht1[4][64], sht2[4][64];
    __shared__ float shph[4];

    {
        const float2* s1 = (const float2*)Ws1;
        #pragma unroll
        for (int r = 0; r < 4; r++) { int e = tid + r * 256; int f = e >> 4, k2 = e & 15;
            float2 v = s1[e]; wlds[PK_W1 + k2 * 64 + f] = pk2(v.x, v.y); }
        const float2* s2 = (const float2*)Ws2;
        #pragma unroll
        for (int r = 0; r < 8; r++) { int e = tid + r * 256; int f = e >> 5, k2 = e & 31;
            float2 v = s2[e]; wlds[PK_W2 + k2 * 64 + f] = pk2(v.x, v.y); }
        const float2* s3 = (const float2*)Ws3;
        #pragma unroll
        for (int r = 0; r < 4; r++) { int e = tid + r * 256; int f = e >> 5, k2 = e & 31;
            float2 v = s3[e]; wlds[PK_W3 + k2 * 32 + f] = pk2(v.x, v.y); }
        const float2* si = (const float2*)Wi1;
        #pragma unroll
        for (int r = 0; r < 16; r++) { int e = tid + r * 256; int f = e >> 6, c2 = e & 63;
            float2 v = si[e]; wlds[PK_WI1 + c2 * 64 + f] = pk2(v.x, v.y); }
        const float2* sc = (const float2*)Wc;
        #pragma unroll
        for (int r = 0; r < 4; r++) { int e = tid + r * 256; int f = e >> 5, c2 = e & 31;
            float2 v = sc[e]; wlds[PK_WC + c2 * 32 + f] = pk2(v.x, v.y); }
    }
    if (blockIdx.x == 0) {
        // Wi2/bi2 UNSCALED: pair epilogue uses Pade tanh, not exp2
        #pragma unroll
        for (int r = 0; r < 16; r++) { int e = tid + r * 256; wsu[U_W2B + e] = f2bf(Wi2[e]); }
        #pragma unroll
        for (int r = 0; r < 8; r++)  { int e = tid + r * 256; wsu[U_W3B + e] = f2bf(Wi3[e]); }
        if (tid < HDIM) ws[WS_BI2 + tid] = bi2[tid];
        if (tid < LDIM) ws[WS_BI3 + tid] = bi3[tid];
    }

    float sv = (t < 33) ? state[i * 33 + t] : 0.f;
    if (t < 32) shh[w][t] = sv;
    if (t == 32) shph[w] = sv;
    if (t == 33) ws[WS_AGG + i] = fast_sigmoid(aggr[i]);
    __syncthreads();

    {
        float s = bs1[t];
        const unsigned int* W = wlds + PK_W1;
        #pragma unroll
        for (int k2 = 0; k2 < 16; k2++) {
            unsigned int p = W[k2 * 64 + t];
            s = fmaf(blo(p), shh[w][2 * k2], s);
            s = fmaf(bhi(p), shh[w][2 * k2 + 1], s);
        }
        sht1[w][t] = fast_tanh(s);
    }
    __syncthreads();
    {
        float s = bs2[t];
        const unsigned int* W = wlds + PK_W2;
        #pragma unroll
        for (int k2 = 0; k2 < 32; k2++) {
            unsigned int p = W[k2 * 64 + t];
            s = fmaf(blo(p), sht1[w][2 * k2], s);
            s = fmaf(bhi(p), sht1[w][2 * k2 + 1], s);
        }
        sht2[w][t] = fast_tanh(s);
    }
    __syncthreads();
    if (t < 32) {
        float s = bs3[t];
        const unsigned int* W = wlds + PK_W3;
        #pragma unroll
        for (int k2 = 0; k2 < 32; k2++) {
            unsigned int p = W[k2 * 32 + t];
            s = fmaf(blo(p), sht2[w][2 * k2], s);
            s = fmaf(bhi(p), sht2[w][2 * k2 + 1], s);
        }
        ws[WS_SELF + i * 32 + t] = s;
        shdh[w][t] = s;
    }
    __syncthreads();
    {
        float sa = 0.f, sb = bi1[t];
        const unsigned int* W = wlds + PK_WI1;
        #pragma unroll
        for (int k2 = 0; k2 < 16; k2++) {
            float h0 = shh[w][2 * k2], h1 = shh[w][2 * k2 + 1];
            float d0 = shdh[w][2 * k2], d1 = shdh[w][2 * k2 + 1];
            unsigned int wa  = W[k2 * 64 + t];
            unsigned int wb  = W[(16 + k2) * 64 + t];
            unsigned int wa2 = W[(32 + k2) * 64 + t];
            unsigned int wb2 = W[(48 + k2) * 64 + t];
            sa = fmaf(blo(wa), h0, sa);  sa = fmaf(bhi(wa), h1, sa);
            sb = fmaf(blo(wb), h0, sb);  sb = fmaf(bhi(wb), h1, sb);
            sa = fmaf(blo(wa2), d0, sa); sa = fmaf(bhi(wa2), d1, sa);
            sb = fmaf(blo(wb2), d0, sb); sb = fmaf(bhi(wb2), d1, sb);
        }
        // exp-factorized: store E = 2^(pre-scaled logit) instead of logit
        ws[WS_AA + i * 64 + t]  = __builtin_amdgcn_exp2f(sa * K2P);
        wsu[U_BJB + i * 64 + t] = f2bf(__builtin_amdgcn_exp2f(sb * K2P));
    }
    if (t < 32) {
        float si2 = 0.f, sj = 0.f;
        const unsigned int* W = wlds + PK_WC;
        #pragma unroll
        for (int m2 = 0; m2 < 16; m2++) {
            float h0 = shh[w][2 * m2], h1 = shh[w][2 * m2 + 1];
            unsigned int wi = W[m2 * 32 + t];
            unsigned int wj = W[(16 + m2) * 32 + t];
            si2 = fmaf(blo(wi), h0, si2); si2 = fmaf(bhi(wi), h1, si2);
            sj  = fmaf(blo(wj), h0, sj);  sj  = fmaf(bhi(wj), h1, sj);
        }
        // Ei = 2^(-log2e*(ci+bc)); sigmoid(ci+cj) = rcp(1 + Ei*Ej)
        ws[WS_CI + i * 32 + t] = __builtin_amdgcn_exp2f((si2 + bc[t]) * K1N);
        float h = shh[w][t];
        wsu[U_HJB + i * 32 + t] = f2bf(h);
        float ejn = __builtin_amdgcn_exp2f(sj * K1N);
        float sc_, cc_;
        __sincosf(shph[w] * phw[t], &sc_, &cc_);
        // pair (l, l+16) into one bf16 uint4 for stage-C pk math
        int p = (t & 15) + 16;                       // partner lane (self for t>=16)
        float h_p  = __shfl(h,   p);
        float e_p  = __shfl(ejn, p);
        float cc_p = __shfl(cc_, p);
        float sc_p = __shfl(sc_, p);
        if (t < 16) {
            uint4 o; o.x = pk2(h, h_p); o.y = pk2(ejn, e_p);
            o.z = pk2(cc_, cc_p); o.w = pk2(sc_, sc_p);
            *(uint4*)(wsu + U_JT + (i * 16 + t) * 8) = o;
        }
    }
}

// ------------- kernel 2: MFMA pairwise core (1 block per i) ---------------
// v9 = R7 revert (verified best: pair 51.5us, absmax 4.0). R8's forced
// VOP3P inline asm REGRESSED (+3.2us, VGPR+4, conflicts x4.5, absmax
// drift 4->10): each asm "=v" def blocks copy-coalescing and operand
// folding, inserting v_movs around every op -- the compiler's native
// selection was already near-optimal. Session model: only net issue-cycle
// removal helps (R3 exp-factorization, R7 deferred-W3); all latency/LDS/
// packing reshuffles were null. Occupancy is grid+VGPR-walled (4 waves/
// SIMD; 64-VGPR tier spills catastrophically, R1). This structure is at
// its practical source-level floor.
__global__ __launch_bounds__(256) void pair_kernel(
    const float* __restrict__ ws, const unsigned short* __restrict__ wsu,
    float* __restrict__ out) {
    const int i    = blockIdx.x;
    const int tid  = threadIdx.x;
    const int w    = tid >> 6;
    const int lane = tid & 63;
    const int q    = lane >> 4;
    const int m    = lane & 15;
    const int jw   = w * 16;
    const int sub  = lane & 3;

    __shared__ unsigned short W2ls[64 * 72];
    __shared__ float redY[4][64];
    __shared__ float redU[4][32], redV[4][32];
    __shared__ float sfw[4];

    // ---- setup ----
    {
        int row = tid >> 2, c = (tid & 3) * 16;
        const uint4* s2 = (const uint4*)(wsu + U_W2B + row * 64 + c);
        uint4 d0 = s2[0], d1 = s2[1];
        uint4* dd = (uint4*)(&W2ls[row * 72 + c]);
        dd[0] = d0; dd[1] = d1;
    }

    v2f hi2[4];                     // own h pairs for fac
    {
        uint4 hv4 = *(const uint4*)(wsu + U_HJB + i * 32 + sub * 8);
        unsigned int hd[4] = {hv4.x, hv4.y, hv4.z, hv4.w};
        #pragma unroll
        for (int e = 0; e < 4; e++) { hi2[e].x = blo(hd[e]); hi2[e].y = bhi(hd[e]); }
    }
    f32x4 b2q[4];              // bias slice for MFMA C-init (unscaled)
    #pragma unroll
    for (int nb = 0; nb < 4; nb++) {
        float4 bv = *(const float4*)(ws + WS_BI2 + nb * 16 + q * 4);
        b2q[nb][0] = bv.x; b2q[nb][1] = bv.y; b2q[nb][2] = bv.z; b2q[nb][3] = bv.w;
    }
    // Ea = 2^(pre-scaled a_i): loop-invariant across all tiles, in registers
    v2f ea2[8];
    {
        const float* ap = ws + WS_AA + i * 64 + q * 8;
        #pragma unroll
        for (int s = 0; s < 2; s++) {
            float4 lo = *(const float4*)(ap + s * 32);
            float4 hi = *(const float4*)(ap + s * 32 + 4);
            ea2[s * 4 + 0].x = lo.x; ea2[s * 4 + 0].y = lo.y;
            ea2[s * 4 + 1].x = lo.z; ea2[s * 4 + 1].y = lo.w;
            ea2[s * 4 + 2].x = hi.x; ea2[s * 4 + 2].y = hi.y;
            ea2[s * 4 + 3].x = hi.z; ea2[s * 4 + 3].y = hi.w;
        }
    }
    v2f hiv2, ei2;             // (l=m, l=m+16) pairs for stage C
    hiv2.x = bf2f(wsu[U_HJB + i * 32 + m]);      hiv2.y = bf2f(wsu[U_HJB + i * 32 + 16 + m]);
    ei2.x = ws[WS_CI + i * 32 + m];              ei2.y = ws[WS_CI + i * 32 + 16 + m];
    const float aggi = ws[WS_AGG + i];
    const float sub0 = (sub == 0) ? 1.0f : 0.0f;

    // ---- streaming pointers + tile-0 prefetch ----
    const unsigned short* hp = wsu + U_HJB + (jw + (lane >> 2)) * 32 + sub * 8;
    const unsigned short* bp = wsu + U_BJB + (jw + m) * 64 + q * 8;
    const unsigned short* jp = wsu + U_JT + ((jw + q * 4) * 16 + m) * 8;

    uint4 hvA = *(const uint4*)hp;
    uint4 b0A = *(const uint4*)bp;
    uint4 b1A = *(const uint4*)(bp + 32);
    uint4 hvB, b0B, b1B;
    __syncthreads();

    // persistent accumulators: Y[n] partials (y2[nb*2+0]={e0,e1}, [nb*2+1]={e2,e3})
    v2f y2[8];
    #pragma unroll
    for (int k = 0; k < 8; k++) { y2[k].x = 0.f; y2[k].y = 0.f; }
    v2f u2; u2.x = 0.f; u2.y = 0.f;
    v2f vv2; vv2.x = 0.f; vv2.y = 0.f;
    float sumfac = 0.f;

    auto body = [&](int T, const uint4& hvc, const uint4& b0c, const uint4& b1c,
                    uint4& hvn, uint4& b0n, uint4& b1n) {
        // prefetch next tile's h/b
        hp += 2048; bp += 4096;
        hvn = *(const uint4*)hp;
        b0n = *(const uint4*)bp;
        b1n = *(const uint4*)(bp + 32);

        // jt loads for CURRENT tile (consumed in stage C)
        uint4 jt4[4];
        #pragma unroll
        for (int r = 0; r < 4; r++) jt4[r] = *(const uint4*)(jp + r * 128);
        jp += 8192;

        // 1) fac (lane owns j = T*64 + jw + (lane>>2)); zeroed at j==i
        float facm;
        {
            unsigned int hd[4] = {hvc.x, hvc.y, hvc.z, hvc.w};
            v2f s2v; s2v.x = 0.f; s2v.y = 0.f;
            #pragma unroll
            for (int e = 0; e < 4; e++) {
                v2f hj; hj.x = blo(hd[e]); hj.y = bhi(hd[e]);
                v2f d = hi2[e] - hj;
                s2v += d * d;                      // v_pk_fma
            }
            float s = s2v.x + s2v.y;
            s += __shfl_xor(s, 1); s += __shfl_xor(s, 2);
            int jj = T * 64 + jw + (lane >> 2);
            float facown = fminf(__builtin_amdgcn_rsqf(s), 2.0f) * aggi;
            facown = (jj == i) ? 0.0f : facown;
            sumfac = fmaf(sub0, facown, sumfac);
            facm = __shfl(facown, 4 * m);
        }

        // 2) x1 B-fragments: factored tanh (pk fma + 2 rcp, no exp2)
        bf16x8 afr[2];
        {
            unsigned int bd[8] = {b0c.x, b0c.y, b0c.z, b0c.w, b1c.x, b1c.y, b1c.z, b1c.w};
            #pragma unroll
            for (int s = 0; s < 2; s++) {
                union { uint4 u4; bf16x8 v; } pkd;
                #pragma unroll
                for (int e = 0; e < 4; e++) {
                    unsigned int bw = bd[s * 4 + e];
                    v2f eb; eb.x = blo(bw); eb.y = bhi(bw);
                    v2f t2 = tanh2_fact(ea2[s * 4 + e], eb);
                    ((unsigned int*)&pkd.u4)[e] = pk2(t2.x, t2.y);
                }
                afr[s] = pkd.v;
            }
        }

        // 3) stage A: X2^T = Wi2' * X1^T, C-init = bias (unscaled logit out)
        f32x4 accA[4];
        #pragma unroll
        for (int nb = 0; nb < 4; nb++) {
            f32x4 acc = b2q[nb];
            #pragma unroll
            for (int s = 0; s < 2; s++) {
                bf16x8 w2f = *(const bf16x8*)(&W2ls[(nb * 16 + m) * 72 + s * 32 + q * 8]);
                acc = __builtin_amdgcn_mfma_f32_16x16x32_bf16(w2f, afr[s], acc, 0, 0, 0);
            }
            accA[nb] = acc;
        }
        // epilogue A: Y[n] += facm * tanh(z), Pade(15,6), f32 register accum
        // (deferred W3 projection -- no pack, no LDS, no stageB MFMA)
        #pragma unroll
        for (int nb = 0; nb < 4; nb++) {
            v2f zA; zA.x = accA[nb][0]; zA.y = accA[nb][1];
            v2f zB; zB.x = accA[nb][2]; zB.y = accA[nb][3];
            v2f zzA = zA * zA, zzB = zB * zB;
            v2f nA = zA * (zzA + 15.0f), nB = zB * (zzB + 15.0f);
            v2f dA = zzA * 6.0f + 15.0f, dB = zzB * 6.0f + 15.0f;
            v2f rA, rB;
            rA.x = fast_rcp(dA.x); rA.y = fast_rcp(dA.y);
            rB.x = fast_rcp(dB.x); rB.y = fast_rcp(dB.y);
            y2[nb * 2 + 0] += nA * (rA * facm);
            y2[nb * 2 + 1] += nB * (rB * facm);
        }

        // 5) stage C: quantum partials; coh = rcp(1 + Ei*Ej), per-elem rcp
        #pragma unroll
        for (int r = 0; r < 4; r++) {
            uint4 jv = jt4[r];
            v2f hj2; hj2.x = blo(jv.x); hj2.y = bhi(jv.x);
            v2f ej2; ej2.x = blo(jv.y); ej2.y = bhi(jv.y);
            v2f pc2; pc2.x = blo(jv.z); pc2.y = bhi(jv.z);
            v2f ps2; ps2.x = blo(jv.w); ps2.y = bhi(jv.w);
            v2f dd = ei2 * ej2 + 1.0f;
            v2f coh; coh.x = fast_rcp(dd.x); coh.y = fast_rcp(dd.y);
            v2f cd = coh * (hiv2 - hj2);
            u2  += cd * pc2;
            vv2 += cd * ps2;
        }
    };

    #pragma unroll 1
    for (int T = 0; T < 16; T += 2) {
        body(T,     hvA, b0A, b1A, hvB, b0B, b1B);
        body(T + 1, hvB, b0B, b1B, hvA, b0A, b1A);
    }

    // ---- final reductions ----
    // Y over the 16 m-lanes (lane bits 0..3); every lane in a q-group ends
    // with the full Y for its n-set {nb*16 + q*4 + e}.
    float yv[16];
    #pragma unroll
    for (int nb = 0; nb < 4; nb++) {
        yv[nb * 4 + 0] = y2[nb * 2 + 0].x; yv[nb * 4 + 1] = y2[nb * 2 + 0].y;
        yv[nb * 4 + 2] = y2[nb * 2 + 1].x; yv[nb * 4 + 3] = y2[nb * 2 + 1].y;
    }
    #pragma unroll
    for (int k = 0; k < 16; k++) {
        yv[k] += __shfl_xor(yv[k], 1); yv[k] += __shfl_xor(yv[k], 2);
        yv[k] += __shfl_xor(yv[k], 4); yv[k] += __shfl_xor(yv[k], 8);
    }
    if (m == 0) {
        #pragma unroll
        for (int nb = 0; nb < 4; nb++) {
            #pragma unroll
            for (int e = 0; e < 4; e++)
                redY[w][nb * 16 + q * 4 + e] = yv[nb * 4 + e];
        }
    }
    float aU[2] = {u2.x, u2.y};
    float aV[2] = {vv2.x, vv2.y};
    #pragma unroll
    for (int lb = 0; lb < 2; lb++) {
        aU[lb] += __shfl_xor(aU[lb], 16); aU[lb] += __shfl_xor(aU[lb], 32);
        aV[lb] += __shfl_xor(aV[lb], 16); aV[lb] += __shfl_xor(aV[lb], 32);
    }
    sumfac += __shfl_xor(sumfac, 1);  sumfac += __shfl_xor(sumfac, 2);
    sumfac += __shfl_xor(sumfac, 4);  sumfac += __shfl_xor(sumfac, 8);
    sumfac += __shfl_xor(sumfac, 16); sumfac += __shfl_xor(sumfac, 32);
    if (lane < 16) {
        redU[w][m] = aU[0];      redU[w][16 + m] = aU[1];
        redV[w][m] = aV[0];      redV[w][16 + m] = aV[1];
    }
    if (lane == 0) sfw[w] = sumfac;
    __syncthreads();
    // combine Y across waves (64 threads, one n each)
    if (tid < 64) {
        redY[0][tid] = (redY[0][tid] + redY[1][tid]) + (redY[2][tid] + redY[3][tid]);
    }
    __syncthreads();
    if (tid < 32) {
        int l = tid;
        // T1[l] = sum_n W3[l,n] * Y[n]  (one-time 64-fma matvec)
        float t1 = 0.f;
        const uint4* w3p = (const uint4*)(wsu + U_W3B + l * 64);
        #pragma unroll
        for (int c = 0; c < 8; c++) {
            uint4 wv = w3p[c];
            unsigned int wd[4] = {wv.x, wv.y, wv.z, wv.w};
            const float* yp = &redY[0][c * 8];
            #pragma unroll
            for (int e = 0; e < 4; e++) {
                t1 = fmaf(blo(wd[e]), yp[2 * e],     t1);
                t1 = fmaf(bhi(wd[e]), yp[2 * e + 1], t1);
            }
        }
        float uu = (redU[0][l] + redU[1][l]) + (redU[2][l] + redU[3][l]);
        float vvv = (redV[0][l] + redV[1][l]) + (redV[2][l] + redV[3][l]);
        float sf = (sfw[0] + sfw[1]) + (sfw[2] + sfw[3]);
        int mm = l & 15;
        uint2 jti = *(const uint2*)(wsu + U_JT + (i * 16 + mm) * 8 + 4);  // cc/sc pair words
        float pic = (l < 16) ? blo(jti.x) : bhi(jti.x);
        float pis = (l < 16) ? blo(jti.y) : bhi(jti.y);
        float isum = t1 + sf * ws[WS_BI3 + l] - (pic * uu + pis * vvv);
        out[i * 33 + l] = 0.5f * ws[WS_SELF + i * 32 + l] + 0.3f * isum;
        // parallel |isum| tail reduce
        float ab = fabsf(isum);
        ab += __shfl_xor(ab, 1); ab += __shfl_xor(ab, 2);
        ab += __shfl_xor(ab, 4); ab += __shfl_xor(ab, 8);
        ab += __shfl_xor(ab, 16);
        if (tid == 0) out[i * 33 + 32] = 0.1f + 0.05f * ab;
    }
}

extern "C" void kernel_launch(void* const* d_in, const int* in_sizes, int n_in,
                              void* d_out, int out_size, void* d_ws, size_t ws_size,
                              hipStream_t stream) {
    const float* state   = (const float*)d_in[0];
    const float* Ws1     = (const float*)d_in[1];
    const float* bs1     = (const float*)d_in[2];
    const float* Ws2     = (const float*)d_in[3];
    const float* bs2     = (const float*)d_in[4];
    const float* Ws3     = (const float*)d_in[5];
    const float* bs3     = (const float*)d_in[6];
    const float* Wi1     = (const float*)d_in[7];
    const float* bi1     = (const float*)d_in[8];
    const float* Wi2     = (const float*)d_in[9];
    const float* bi2     = (const float*)d_in[10];
    const float* Wi3     = (const float*)d_in[11];
    const float* bi3     = (const float*)d_in[12];
    const float* phase_w = (const float*)d_in[13];
    const float* Wc      = (const float*)d_in[14];
    const float* bc      = (const float*)d_in[15];
    const float* aggr    = (const float*)d_in[16];

    float* ws = (float*)d_ws;
    unsigned short* wsu = (unsigned short*)(ws + WS_FEND);
    float* out = (float*)d_out;

    precompute<<<256, 256, 0, stream>>>(state, Ws1, bs1, Ws2, bs2, Ws3, bs3,
                                        Wi1, bi1, Wi2, bi2, Wi3, bi3,
                                        phase_w, Wc, bc, aggr, ws, wsu);
    pair_kernel<<<NN, 256, 0, stream>>>(ws, wsu, out);
}